// Round 2
// baseline (4202.970 us; speedup 1.0000x reference)
//
#include <hip/hip_runtime.h>
#include <stdint.h>
#include <math.h>

// Problem constants (match reference)
#define BB 32
#define NWW 500
#define NSS 50
#define SLL 40
#define EMBD 300
#define HIDD 150
#define EDGES 563200
#define NSENT 1600      // B*NS
#define NNODES 17600    // B*(NW+NS)
#define OUT0SZ 2640000  // 17600*150
#define OUT1SZ 4800000  // 32*500*300

__device__ __forceinline__ float sigm(float x){ return 1.f / (1.f + expf(-x)); }

// ---------------- POS table (numpy float64 sinusoid, row 0 zeroed) ----------
__global__ void gcnk_postab(float* __restrict__ pos){
  int idx = blockIdx.x * 256 + threadIdx.x;
  if (idx >= 513 * 300) return;
  int p = idx / 300, i = idx - p * 300;
  float v = 0.f;
  if (p != 0){
    double expo = (double)(2 * (i / 2)) / 300.0;
    double ang = (double)p / pow(10000.0, expo);
    v = (float)((i & 1) ? cos(ang) : sin(ang));
  }
  pos[idx] = v;
}

// ---------------- sentlen (nonzero tokens) + glen (nonzero first-token) -----
__global__ void gcnk_prep(const int* __restrict__ sx, int* __restrict__ sentlen,
                          int* __restrict__ glen){
  int tid = blockIdx.x * 256 + threadIdx.x;
  if (tid < 1600){
    int c = 0;
    for (int j = 0; j < 40; j++) c += (sx[tid * 40 + j] != 0);
    sentlen[tid] = c;
  } else if (tid < 1632){
    int b = tid - 1600, c = 0;
    for (int s = 0; s < 50; s++) c += (sx[b * 2000 + s * 40] != 0);
    glen[b] = c;
  }
}

// rowmap[b*50+t] = b*50 + (t<glen ? glen-1-t : t)   (involution)
__global__ void gcnk_rowmap(const int* __restrict__ glen, int* __restrict__ rowmap){
  int i = blockIdx.x * 256 + threadIdx.x;
  if (i >= 1600) return;
  int b = i / 50, t = i - b * 50, g = glen[b];
  rowmap[i] = b * 50 + ((t < g) ? (g - 1 - t) : t);
}

// ---------------- emb_words output: row-gather copy (float4) ----------------
__global__ void gcnk_embw(const int* __restrict__ x, const float* __restrict__ tab,
                          float4* __restrict__ out){
  int idx = blockIdx.x * 256 + threadIdx.x;
  if (idx >= 16000 * 75) return;
  int row = idx / 75, q = idx - row * 75;
  const float4* t = (const float4*)tab;
  out[idx] = t[x[row] * 75 + q];
}

// ---------------- CNN per-sentence conv + relu + maxpool --------------------
template<int H>
__device__ void conv_head(const float* __restrict__ enc, const float* __restrict__ w,
                          const float* __restrict__ bias, float* __restrict__ ngram_row,
                          int lane){
  if (lane >= 50) return;
  const int LH = 41 - H;
  float acc[LH];
  #pragma unroll
  for (int l = 0; l < LH; l++) acc[l] = 0.f;
  const float* wrow = w + lane * (H * 300);
  #pragma unroll 1
  for (int k = 0; k < H; k++){
    const float* wk = wrow + k * 300;
    const float* ek = enc + k * 300;
    #pragma unroll 1
    for (int d4 = 0; d4 < 75; d4++){
      const float4 wv = *(const float4*)(wk + d4 * 4);
      #pragma unroll
      for (int l = 0; l < LH; l++){
        const float4 e = *(const float4*)(ek + l * 300 + d4 * 4);
        acc[l] += e.x * wv.x + e.y * wv.y + e.z * wv.z + e.w * wv.w;
      }
    }
  }
  float bv = bias[lane];
  float m = 0.f;  // relu>=0, so 0 is a valid max identity
  #pragma unroll
  for (int l = 0; l < LH; l++){
    float v = acc[l] + bv;
    if (v > m) m = v;
  }
  ngram_row[(H - 2) * 50 + lane] = m;
}

__global__ __launch_bounds__(384)
void gcnk_conv(const int* __restrict__ sx, const float* __restrict__ tab,
               const float* __restrict__ pos, const int* __restrict__ sentlen,
               const float* w2, const float* c2, const float* w3, const float* c3,
               const float* w4, const float* c4, const float* w5, const float* c5,
               const float* w6, const float* c6, const float* w7, const float* c7,
               float* __restrict__ ngram){
  __shared__ float enc[12000];  // 40 x 300, 48 KB
  __shared__ int toks[40];
  int n = blockIdx.x, tid = threadIdx.x;
  if (tid < 40) toks[tid] = sx[n * 40 + tid];
  __syncthreads();
  int slen = sentlen[n];
  for (int idx = tid; idx < 12000; idx += 384){
    int l = idx / 300, d = idx - l * 300;
    int p = (l < slen) ? (l + 1) : 0;
    enc[idx] = tab[toks[l] * 300 + d] + pos[p * 300 + d];
  }
  __syncthreads();
  int wave = tid >> 6, lane = tid & 63;
  float* row = ngram + n * 300;
  switch (wave){
    case 0: conv_head<2>(enc, w2, c2, row, lane); break;
    case 1: conv_head<3>(enc, w3, c3, row, lane); break;
    case 2: conv_head<4>(enc, w4, c4, row, lane); break;
    case 3: conv_head<5>(enc, w5, c5, row, lane); break;
    case 4: conv_head<6>(enc, w6, c6, row, lane); break;
    default: conv_head<7>(enc, w7, c7, row, lane); break;
  }
}

// ngram += POS_TAB[n % 50]
__global__ void gcnk_addpos(float* __restrict__ ngram, const float* __restrict__ pos){
  int idx = blockIdx.x * 256 + threadIdx.x;
  if (idx >= 1600 * 300) return;
  int row = idx / 300, d = idx - row * 300;
  ngram[idx] += pos[(row % 50) * 300 + d];
}

// ---------------- generic fp32 GEMM: C[M,N] = A[M,K] * W[N,K]^T + b1 + b2 ---
__global__ __launch_bounds__(256)
void gcnk_gemm(const float* __restrict__ A, const float* __restrict__ Wt,
               const float* __restrict__ bias1, const float* __restrict__ bias2,
               float* __restrict__ C, int M, int N, int K){
  __shared__ float As[32][34];  // [k][m]
  __shared__ float Ws[32][68];  // [k][n]
  const int tid = threadIdx.x;
  const int m0 = blockIdx.x * 32, n0 = blockIdx.y * 64;
  const int i = tid >> 4, j = tid & 15;
  float acc[2][4] = {{0.f,0.f,0.f,0.f},{0.f,0.f,0.f,0.f}};
  for (int kc = 0; kc < K; kc += 32){
    #pragma unroll
    for (int t = 0; t < 4; t++){
      int idx = tid + t * 256;
      int r = idx >> 5, c = idx & 31;
      int gm = m0 + r, gk = kc + c;
      As[c][r] = (gm < M && gk < K) ? A[gm * K + gk] : 0.f;
    }
    #pragma unroll
    for (int t = 0; t < 8; t++){
      int idx = tid + t * 256;
      int r = idx & 63, c = idx >> 6;
      int gn = n0 + r, gk = kc + c;
      Ws[c][r] = (gn < N && gk < K) ? Wt[gn * K + gk] : 0.f;
    }
    __syncthreads();
    #pragma unroll
    for (int kk = 0; kk < 32; kk++){
      const float2 a = *(const float2*)&As[kk][2 * i];
      const float4 w = *(const float4*)&Ws[kk][4 * j];
      acc[0][0] += a.x * w.x; acc[0][1] += a.x * w.y; acc[0][2] += a.x * w.z; acc[0][3] += a.x * w.w;
      acc[1][0] += a.y * w.x; acc[1][1] += a.y * w.y; acc[1][2] += a.y * w.z; acc[1][3] += a.y * w.w;
    }
    __syncthreads();
  }
  #pragma unroll
  for (int r = 0; r < 2; r++){
    int gm = m0 + 2 * i + r;
    if (gm >= M) continue;
    #pragma unroll
    for (int cc = 0; cc < 4; cc++){
      int gn = n0 + 4 * j + cc;
      if (gn >= N) continue;
      float v = acc[r][cc];
      if (bias1) v += bias1[gn];
      if (bias2) v += bias2[gn];
      C[gm * N + gn] = v;
    }
  }
}

// ---------------- row permute (width 150) -----------------------------------
__global__ void gcnk_permute150(float* __restrict__ dst, const float* __restrict__ src,
                                const int* __restrict__ map){
  int idx = blockIdx.x * 256 + threadIdx.x;
  if (idx >= 1600 * 150) return;
  int row = idx / 150, d = idx - row * 150;
  dst[idx] = src[map[row] * 150 + d];
}

// dst[row] = [ A[mapA(row)], B[mapB(row)] ]  (each 150 wide), optional t<glen mask
__global__ void gcnk_concat(float* __restrict__ dst, const float* __restrict__ A,
                            const float* __restrict__ Bs, const int* __restrict__ mapA,
                            const int* __restrict__ mapB, const int* __restrict__ glen,
                            int usemask){
  int idx = blockIdx.x * 256 + threadIdx.x;
  if (idx >= 1600 * 300) return;
  int row = idx / 300, d = idx - row * 300;
  int b = row / 50, t = row - b * 50;
  float v;
  if (d < 150){ int r = mapA ? mapA[row] : row; v = A[r * 150 + d]; }
  else        { int r = mapB ? mapB[row] : row; v = Bs[r * 150 + d - 150]; }
  if (usemask && t >= glen[b]) v = 0.f;
  dst[idx] = v;
}

// ---------------- LSTM recurrence (x-projection precomputed) ----------------
__global__ __launch_bounds__(320)
void gcnk_lstm(const float* __restrict__ xf, const float* __restrict__ xr,
               const float* __restrict__ whh, float* __restrict__ fo,
               float* __restrict__ ro){
  int b = blockIdx.x >> 1, dir = blockIdx.x & 1;
  const float* xih = dir ? xr : xf;
  const float* W = whh + dir * 600 * 150;
  float* out = dir ? ro : fo;
  __shared__ float h[152];
  __shared__ float gates[600];
  int tid = threadIdx.x;
  for (int u = tid; u < 150; u += 320) h[u] = 0.f;
  float creg = 0.f;
  __syncthreads();
  for (int t = 0; t < 50; t++){
    const float* xrow = xih + (b * 50 + t) * 600;
    #pragma unroll
    for (int k = 0; k < 2; k++){
      int g = k * 320 + tid;
      if (g < 600){
        const float* wr = W + g * 150;
        float sum = 0.f;
        #pragma unroll 5
        for (int u = 0; u < 150; u += 2){
          const float2 w2 = *(const float2*)(wr + u);
          sum += h[u] * w2.x + h[u + 1] * w2.y;
        }
        gates[g] = xrow[g] + sum;
      }
    }
    __syncthreads();
    if (tid < 150){
      float ig = sigm(gates[tid]);
      float fg = sigm(gates[150 + tid]);
      float gg = tanhf(gates[300 + tid]);
      float og = sigm(gates[450 + tid]);
      creg = fg * creg + ig * gg;
      float hn = og * tanhf(creg);
      h[tid] = hn;
      out[(b * 50 + t) * 150 + tid] = hn;
    }
    __syncthreads();
  }
}

// ---------------- node feature assembly [17600 x 300] -----------------------
__global__ void gcnk_nodes_in(const int* __restrict__ x, const float* __restrict__ tab,
                              const float* __restrict__ cnnf, const float* __restrict__ lstmf,
                              float* __restrict__ out){
  int idx = blockIdx.x * 256 + threadIdx.x;
  if (idx >= NNODES * 300) return;
  int nrow = idx / 300, d = idx - nrow * 300;
  int b = nrow / 550, j = nrow - b * 550;
  float v;
  if (j < 500) v = tab[x[b * 500 + j] * 300 + d];
  else {
    int r = b * 50 + (j - 500);
    v = (d < 150) ? cnnf[r * 150 + d] : lstmf[r * 150 + d - 150];
  }
  out[idx] = v;
}

// ---------------- GCN normalization + scatter -------------------------------
__global__ void gcnk_deginit(float* __restrict__ deg){
  int i = blockIdx.x * 256 + threadIdx.x;
  if (i < NNODES) deg[i] = 1.0f;  // self-loop
}
__global__ void gcnk_degedges(const int* __restrict__ ei, float* __restrict__ deg){
  int e = blockIdx.x * 256 + threadIdx.x;
  if (e < EDGES) atomicAdd(&deg[ei[EDGES + e]], 1.0f);
}
__global__ void gcnk_dis(const float* __restrict__ deg, float* __restrict__ dis){
  int i = blockIdx.x * 256 + threadIdx.x;
  if (i < NNODES) dis[i] = (deg[i] > 0.f) ? rsqrtf(deg[i]) : 0.f;
}
// agg init with self-loop term: agg[n] = xw[n] * dis[n]^2
__global__ void gcnk_agg_init(float* __restrict__ agg, const float* __restrict__ xw,
                              const float* __restrict__ dis){
  int idx = blockIdx.x * 256 + threadIdx.x;
  if (idx >= NNODES * 150) return;
  int n = idx / 150;
  float d = dis[n];
  agg[idx] = xw[idx] * d * d;
}
__global__ void gcnk_agg_edges(const int* __restrict__ ei, const float* __restrict__ dis,
                               const float* __restrict__ xw, float* __restrict__ agg){
  int gtid = blockIdx.x * 256 + threadIdx.x;
  int wid = gtid >> 6, lane = gtid & 63;
  int nw = (gridDim.x * 256) >> 6;
  for (int e = wid; e < EDGES; e += nw){
    int s = ei[e], d = ei[EDGES + e];
    float coef = dis[s] * dis[d];
    const float* xs = xw + s * 150;
    float* ad = agg + d * 150;
    atomicAdd(ad + lane,      xs[lane]      * coef);
    atomicAdd(ad + lane + 64, xs[lane + 64] * coef);
    if (lane < 22) atomicAdd(ad + lane + 128, xs[lane + 128] * coef);
  }
}
__global__ void gcnk_elu(float* __restrict__ h, const float* __restrict__ agg,
                         const float* __restrict__ bias){
  int idx = blockIdx.x * 256 + threadIdx.x;
  if (idx >= NNODES * 150) return;
  int c = idx % 150;
  float v = agg[idx] + bias[c];
  h[idx] = (v > 0.f) ? v : expm1f(v);
}
__global__ void gcnk_out0(float* __restrict__ out, const float* __restrict__ agg,
                          const float* __restrict__ bias){
  int idx = blockIdx.x * 256 + threadIdx.x;
  if (idx >= NNODES * 150) return;
  int c = idx % 150;
  out[idx] = agg[idx] + bias[c];
}

// ============================================================================
extern "C" void kernel_launch(void* const* d_in, const int* in_sizes, int n_in,
                              void* d_out, int out_size, void* d_ws, size_t ws_size,
                              hipStream_t stream){
  (void)in_sizes; (void)n_in; (void)out_size; (void)ws_size;

  // ---- workspace carve-out (all buffers fully written before read) ----
  char* wsb = (char*)d_ws;
  size_t off = 0;
  auto alloc = [&](size_t bytes) -> void* {
    void* p = wsb + off;
    off = (off + bytes + 255) & ~(size_t)255;
    return p;
  };
  float* pos_tab  = (float*)alloc(513 * 300 * 4);
  int*   sentlen  = (int*)alloc(1600 * 4);
  int*   glen     = (int*)alloc(32 * 4);
  int*   rowmap   = (int*)alloc(1600 * 4);
  float* ngram    = (float*)alloc(1600 * 300 * 4);
  float* cnn_feat = (float*)alloc(1600 * 150 * 4);
  float* cnn_rev  = (float*)alloc(1600 * 150 * 4);
  float* xih_f    = (float*)alloc(1600 * 600 * 4);
  float* xih_r    = (float*)alloc(1600 * 600 * 4);
  float* f0       = (float*)alloc(1600 * 150 * 4);
  float* r0       = (float*)alloc(1600 * 150 * 4);
  float* f1       = (float*)alloc(1600 * 150 * 4);
  float* r1       = (float*)alloc(1600 * 150 * 4);
  float* h1       = (float*)alloc(1600 * 300 * 4);
  float* h1rev    = (float*)alloc(1600 * 300 * 4);
  float* hm       = (float*)alloc(1600 * 300 * 4);
  float* lstm_ft  = (float*)alloc(1600 * 150 * 4);
  float* nodes_in = (float*)alloc((size_t)NNODES * 300 * 4);
  float* nodes    = (float*)alloc((size_t)NNODES * 150 * 4);
  float* deg      = (float*)alloc(NNODES * 4);
  float* dis      = (float*)alloc(NNODES * 4);
  float* xw       = (float*)alloc((size_t)NNODES * 150 * 4);
  float* agg      = (float*)alloc((size_t)NNODES * 150 * 4);

  // ---- inputs (ALL floats are fp32 per the reference; ints are int32) ----
  const int*   x   = (const int*)d_in[0];
  const int*   sx  = (const int*)d_in[1];
  const int*   ei  = (const int*)d_in[2];
  const float* tab = (const float*)d_in[3];
  const float *cw[6], *cb[6];
  for (int h = 0; h < 6; h++){ cw[h] = (const float*)d_in[4 + 2 * h]; cb[h] = (const float*)d_in[5 + 2 * h]; }
  const float* cnnw = (const float*)d_in[16]; const float* cnnb = (const float*)d_in[17];
  const float* wih0 = (const float*)d_in[18]; const float* whh0 = (const float*)d_in[19];
  const float* bih0 = (const float*)d_in[20]; const float* bhh0 = (const float*)d_in[21];
  const float* wih1 = (const float*)d_in[22]; const float* whh1 = (const float*)d_in[23];
  const float* bih1 = (const float*)d_in[24]; const float* bhh1 = (const float*)d_in[25];
  const float* lpw  = (const float*)d_in[26]; const float* lpb  = (const float*)d_in[27];
  const float* g0w  = (const float*)d_in[28]; const float* g0b  = (const float*)d_in[29];
  const float* g1w  = (const float*)d_in[30]; const float* g1b  = (const float*)d_in[31];
  const float* g2w  = (const float*)d_in[32]; const float* g2b  = (const float*)d_in[33];

  float* out0 = (float*)d_out;
  float4* out1 = (float4*)((float*)d_out + OUT0SZ);

  auto gemm = [&](const float* A, const float* W, const float* b1, const float* b2,
                  float* C, int M, int N, int K){
    dim3 g((M + 31) / 32, (N + 63) / 64);
    gcnk_gemm<<<g, 256, 0, stream>>>(A, W, b1, b2, C, M, N, K);
  };

  // ---- pipeline ----
  gcnk_postab<<<602, 256, 0, stream>>>(pos_tab);
  gcnk_prep<<<7, 256, 0, stream>>>(sx, sentlen, glen);
  gcnk_rowmap<<<7, 256, 0, stream>>>(glen, rowmap);
  gcnk_embw<<<4688, 256, 0, stream>>>(x, tab, out1);

  gcnk_conv<<<1600, 384, 0, stream>>>(sx, tab, pos_tab, sentlen,
      cw[0], cb[0], cw[1], cb[1], cw[2], cb[2], cw[3], cb[3], cw[4], cb[4], cw[5], cb[5],
      ngram);
  gcnk_addpos<<<1875, 256, 0, stream>>>(ngram, pos_tab);
  gemm(ngram, cnnw, cnnb, nullptr, cnn_feat, 1600, 150, 300);

  // BiLSTM layer 0
  gcnk_permute150<<<938, 256, 0, stream>>>(cnn_rev, cnn_feat, rowmap);
  gemm(cnn_feat, wih0,             bih0,       bhh0,       xih_f, 1600, 600, 150);
  gemm(cnn_rev,  wih0 + 600 * 150, bih0 + 600, bhh0 + 600, xih_r, 1600, 600, 150);
  gcnk_lstm<<<64, 320, 0, stream>>>(xih_f, xih_r, whh0, f0, r0);

  // BiLSTM layer 1
  gcnk_concat<<<1875, 256, 0, stream>>>(h1,    f0, r0, nullptr, rowmap, glen, 0);
  gcnk_concat<<<1875, 256, 0, stream>>>(h1rev, f0, r0, rowmap, nullptr, glen, 0);
  gemm(h1,    wih1,             bih1,       bhh1,       xih_f, 1600, 600, 300);
  gemm(h1rev, wih1 + 600 * 300, bih1 + 600, bhh1 + 600, xih_r, 1600, 600, 300);
  gcnk_lstm<<<64, 320, 0, stream>>>(xih_f, xih_r, whh1, f1, r1);

  // masked projection
  gcnk_concat<<<1875, 256, 0, stream>>>(hm, f1, r1, nullptr, rowmap, glen, 1);
  gemm(hm, lpw, lpb, nullptr, lstm_ft, 1600, 150, 300);

  // node features + gc0
  gcnk_nodes_in<<<20625, 256, 0, stream>>>(x, tab, cnn_feat, lstm_ft, nodes_in);
  gemm(nodes_in, g0w, g0b, nullptr, nodes, NNODES, 150, 300);

  // degree norm
  gcnk_deginit<<<69, 256, 0, stream>>>(deg);
  gcnk_degedges<<<2200, 256, 0, stream>>>(ei, deg);
  gcnk_dis<<<69, 256, 0, stream>>>(deg, dis);

  // gc1 + elu
  gemm(nodes, g1w, nullptr, nullptr, xw, NNODES, 150, 150);
  gcnk_agg_init<<<10313, 256, 0, stream>>>(agg, xw, dis);
  gcnk_agg_edges<<<4096, 256, 0, stream>>>(ei, dis, xw, agg);
  gcnk_elu<<<10313, 256, 0, stream>>>(nodes, agg, g1b);  // h overwrites nodes

  // gc2 -> output 0
  gemm(nodes, g2w, nullptr, nullptr, xw, NNODES, 150, 150);
  gcnk_agg_init<<<10313, 256, 0, stream>>>(agg, xw, dis);
  gcnk_agg_edges<<<4096, 256, 0, stream>>>(ei, dis, xw, agg);
  gcnk_out0<<<10313, 256, 0, stream>>>(out0, agg, g2b);
}

// Round 3
// 2485.187 us; speedup vs baseline: 1.6912x; 1.6912x over previous
//
#include <hip/hip_runtime.h>
#include <stdint.h>
#include <math.h>

// Problem constants (match reference)
#define EDGES 563200
#define NNODES 17600    // B*(NW+NS)
#define OUT0SZ 2640000  // 17600*150
#define MROWS 64000     // 1600 sentences * 40 positions
#define MPAD  64016     // + zero pad rows for window overhang

typedef _Float16 h2 __attribute__((ext_vector_type(2)));

__device__ __forceinline__ float sigm(float x){ return 1.f / (1.f + expf(-x)); }

__device__ __forceinline__ float fdot2_(h2 a, h2 b, float c){
#if __has_builtin(__builtin_amdgcn_fdot2)
  return __builtin_amdgcn_fdot2(a, b, c, false);
#else
  return c + (float)a.x * (float)b.x + (float)a.y * (float)b.y;
#endif
}

// ---------------- POS table (numpy float64 sinusoid, row 0 zeroed) ----------
__global__ void gcnk_postab(float* __restrict__ pos){
  int idx = blockIdx.x * 256 + threadIdx.x;
  if (idx >= 513 * 300) return;
  int p = idx / 300, i = idx - p * 300;
  float v = 0.f;
  if (p != 0){
    double expo = (double)(2 * (i / 2)) / 300.0;
    double ang = (double)p / pow(10000.0, expo);
    v = (float)((i & 1) ? cos(ang) : sin(ang));
  }
  pos[idx] = v;
}

// ---------------- sentlen + glen --------------------------------------------
__global__ void gcnk_prep(const int* __restrict__ sx, int* __restrict__ sentlen,
                          int* __restrict__ glen){
  int tid = blockIdx.x * 256 + threadIdx.x;
  if (tid < 1600){
    int c = 0;
    for (int j = 0; j < 40; j++) c += (sx[tid * 40 + j] != 0);
    sentlen[tid] = c;
  } else if (tid < 1632){
    int b = tid - 1600, c = 0;
    for (int s = 0; s < 50; s++) c += (sx[b * 2000 + s * 40] != 0);
    glen[b] = c;
  }
}

__global__ void gcnk_rowmap(const int* __restrict__ glen, int* __restrict__ rowmap){
  int i = blockIdx.x * 256 + threadIdx.x;
  if (i >= 1600) return;
  int b = i / 50, t = i - b * 50, g = glen[b];
  rowmap[i] = b * 50 + ((t < g) ? (g - 1 - t) : t);
}

// ---------------- emb_words output ------------------------------------------
__global__ void gcnk_embw(const int* __restrict__ x, const float* __restrict__ tab,
                          float4* __restrict__ out){
  int idx = blockIdx.x * 256 + threadIdx.x;
  if (idx >= 16000 * 75) return;
  int row = idx / 75, q = idx - row * 75;
  const float4* t = (const float4*)tab;
  out[idx] = t[x[row] * 75 + q];
}

// ---------------- generic zero ----------------------------------------------
__global__ void gcnk_zeroi(unsigned int* __restrict__ p, int n){
  int i = blockIdx.x * 256 + threadIdx.x;
  if (i < n) p[i] = 0u;
}

// ---------------- enc (fp16): enc[m][d] = tab[tok]+pos, pad rows zero -------
__global__ void gcnk_ench(const int* __restrict__ sx, const float* __restrict__ tab,
                          const float* __restrict__ pos, const int* __restrict__ sentlen,
                          _Float16* __restrict__ ench){
  int idx = blockIdx.x * 256 + threadIdx.x;
  if (idx >= MPAD * 300) return;
  int row = idx / 300, d = idx - row * 300;
  float v = 0.f;
  if (row < MROWS){
    int n = row / 40, l = row - n * 40;
    int tok = sx[n * 40 + l];
    int p = (l < sentlen[n]) ? (l + 1) : 0;
    v = tab[tok * 300 + d] + pos[p * 300 + d];
  }
  ench[idx] = (_Float16)v;
}

// ---------------- conv weights -> fp16, concatenated per head ---------------
__global__ void gcnk_wpack(const float* w2, const float* w3, const float* w4,
                           const float* w5, const float* w6, const float* w7,
                           _Float16* __restrict__ vh){
  int idx = blockIdx.x * 256 + threadIdx.x;
  if (idx >= 405000) return;
  // offsets (halfs): H=2:0, 3:30000, 4:75000, 5:135000, 6:210000, 7:300000
  const float* src; int off;
  if      (idx < 30000) { src = w2; off = 0; }
  else if (idx < 75000) { src = w3; off = 30000; }
  else if (idx < 135000){ src = w4; off = 75000; }
  else if (idx < 210000){ src = w5; off = 135000; }
  else if (idx < 300000){ src = w6; off = 210000; }
  else                  { src = w7; off = 300000; }
  vh[idx] = (_Float16)src[idx - off];
}

// ---------------- conv as implicit-im2col GEMM (fp16 in, fp32 acc) ----------
// A[m][kk] = enc_flat[m*300 + kk]  (lda=300, K=300*H), B = weights [50 x K]
// epilogue: fused relu + window-max via uint atomicMax into ngram.
__global__ __launch_bounds__(256)
void gcnk_convgemm(const h2* __restrict__ A2, const h2* __restrict__ B2,
                   const float* __restrict__ bias, unsigned int* __restrict__ ngram_u,
                   int K, int H){
  __shared__ float smem[128 * 65];           // 33.3 KB
  h2* As = (h2*)smem;                         // [32][128]
  h2* Bs = (h2*)(smem + 4096);                // [32][64]
  const int tid = threadIdx.x;
  const int m0 = blockIdx.x * 128;
  const int tn = tid & 15, tm = tid >> 4;     // micro-tile 8(m) x 4(n)
  const int K2 = K >> 1;
  const int nchunks = (K + 63) / 64;
  const int ar = tid & 127, ahi = tid >> 7;   // A stage: 16 h2 each
  const int br = tid & 63,  bhi = tid >> 6;   // B stage: 8 h2 each
  float acc[8][4] = {};
  for (int ch = 0; ch < nchunks; ch++){
    int kc2 = ch * 32;
    { // stage A (reads may exceed K2 on last chunk: killed by B zeros; pad rows keep in-bounds)
      const h2* g = A2 + (size_t)(m0 + ar) * 150 + kc2 + ahi * 16;
      #pragma unroll
      for (int j = 0; j < 16; j++) As[(ahi * 16 + j) * 128 + ar] = g[j];
    }
    { // stage B with zero-fill (gn >= 50 or k >= K)
      int c2 = kc2 + bhi * 8;
      const h2* g = B2 + (size_t)br * K2 + c2;
      #pragma unroll
      for (int j = 0; j < 8; j++){
        h2 v; v.x = (_Float16)0; v.y = (_Float16)0;
        if (br < 50 && (c2 + j) < K2) v = g[j];
        Bs[(bhi * 8 + j) * 64 + br] = v;
      }
    }
    __syncthreads();
    #pragma unroll
    for (int kk = 0; kk < 32; kk++){
      h2 a[8], b[4];
      #pragma unroll
      for (int i = 0; i < 8; i++) a[i] = As[kk * 128 + tm * 8 + i];
      #pragma unroll
      for (int j = 0; j < 4; j++) b[j] = Bs[kk * 64 + tn * 4 + j];
      #pragma unroll
      for (int i = 0; i < 8; i++)
        #pragma unroll
        for (int j = 0; j < 4; j++)
          acc[i][j] = fdot2_(a[i], b[j], acc[i][j]);
    }
    __syncthreads();
  }
  // epilogue: acc -> LDS, then per-(sentence,o) relu-max + atomicMax
  #pragma unroll
  for (int i = 0; i < 8; i++)
    #pragma unroll
    for (int j = 0; j < 4; j++)
      smem[(tm * 8 + i) * 65 + tn * 4 + j] = acc[i][j];
  __syncthreads();
  if (tid < 250){
    int nl = tid / 50, o = tid - nl * 50;
    int n = m0 / 40 + nl;
    if (n < 1600){
      int lh = 41 - H;
      int l_lo = m0 - n * 40; if (l_lo < 0) l_lo = 0;
      int l_hi = m0 + 128 - n * 40; if (l_hi > lh) l_hi = lh;
      if (l_lo < l_hi){
        float bv = bias[o];
        float vmax = 0.f;
        for (int l = l_lo; l < l_hi; l++){
          float v = smem[(n * 40 + l - m0) * 65 + o] + bv;
          vmax = fmaxf(vmax, v);
        }
        atomicMax(ngram_u + n * 300 + (H - 2) * 50 + o, __float_as_uint(vmax));
      }
    }
  }
}

// ngram += POS_TAB[n % 50]
__global__ void gcnk_addpos(float* __restrict__ ngram, const float* __restrict__ pos){
  int idx = blockIdx.x * 256 + threadIdx.x;
  if (idx >= 1600 * 300) return;
  int row = idx / 300, d = idx - row * 300;
  ngram[idx] += pos[(row % 50) * 300 + d];
}

// ---------------- generic fp32 GEMM: C[M,N] = A[M,K] * W[N,K]^T + b1 + b2 ---
__global__ __launch_bounds__(256)
void gcnk_gemm(const float* __restrict__ A, const float* __restrict__ Wt,
               const float* __restrict__ bias1, const float* __restrict__ bias2,
               float* __restrict__ C, int M, int N, int K){
  __shared__ float As[32][34];
  __shared__ float Ws[32][68];
  const int tid = threadIdx.x;
  const int m0 = blockIdx.x * 32, n0 = blockIdx.y * 64;
  const int i = tid >> 4, j = tid & 15;
  float acc[2][4] = {{0.f,0.f,0.f,0.f},{0.f,0.f,0.f,0.f}};
  for (int kc = 0; kc < K; kc += 32){
    #pragma unroll
    for (int t = 0; t < 4; t++){
      int idx = tid + t * 256;
      int r = idx >> 5, c = idx & 31;
      int gm = m0 + r, gk = kc + c;
      As[c][r] = (gm < M && gk < K) ? A[gm * K + gk] : 0.f;
    }
    #pragma unroll
    for (int t = 0; t < 8; t++){
      int idx = tid + t * 256;
      int r = idx & 63, c = idx >> 6;
      int gn = n0 + r, gk = kc + c;
      Ws[c][r] = (gn < N && gk < K) ? Wt[gn * K + gk] : 0.f;
    }
    __syncthreads();
    #pragma unroll
    for (int kk = 0; kk < 32; kk++){
      const float2 a = *(const float2*)&As[kk][2 * i];
      const float4 w = *(const float4*)&Ws[kk][4 * j];
      acc[0][0] += a.x * w.x; acc[0][1] += a.x * w.y; acc[0][2] += a.x * w.z; acc[0][3] += a.x * w.w;
      acc[1][0] += a.y * w.x; acc[1][1] += a.y * w.y; acc[1][2] += a.y * w.z; acc[1][3] += a.y * w.w;
    }
    __syncthreads();
  }
  #pragma unroll
  for (int r = 0; r < 2; r++){
    int gm = m0 + 2 * i + r;
    if (gm >= M) continue;
    #pragma unroll
    for (int cc = 0; cc < 4; cc++){
      int gn = n0 + 4 * j + cc;
      if (gn >= N) continue;
      float v = acc[r][cc];
      if (bias1) v += bias1[gn];
      if (bias2) v += bias2[gn];
      C[gm * N + gn] = v;
    }
  }
}

// ---------------- row permute / concat --------------------------------------
__global__ void gcnk_permute150(float* __restrict__ dst, const float* __restrict__ src,
                                const int* __restrict__ map){
  int idx = blockIdx.x * 256 + threadIdx.x;
  if (idx >= 1600 * 150) return;
  int row = idx / 150, d = idx - row * 150;
  dst[idx] = src[map[row] * 150 + d];
}

__global__ void gcnk_concat(float* __restrict__ dst, const float* __restrict__ A,
                            const float* __restrict__ Bs, const int* __restrict__ mapA,
                            const int* __restrict__ mapB, const int* __restrict__ glen,
                            int usemask){
  int idx = blockIdx.x * 256 + threadIdx.x;
  if (idx >= 1600 * 300) return;
  int row = idx / 300, d = idx - row * 300;
  int b = row / 50, t = row - b * 50;
  float v;
  if (d < 150){ int r = mapA ? mapA[row] : row; v = A[r * 150 + d]; }
  else        { int r = mapB ? mapB[row] : row; v = Bs[r * 150 + d - 150]; }
  if (usemask && t >= glen[b]) v = 0.f;
  dst[idx] = v;
}

// ---------------- LSTM recurrence (x-projection precomputed) ----------------
__global__ __launch_bounds__(320)
void gcnk_lstm(const float* __restrict__ xf, const float* __restrict__ xr,
               const float* __restrict__ whh, float* __restrict__ fo,
               float* __restrict__ ro){
  int b = blockIdx.x >> 1, dir = blockIdx.x & 1;
  const float* xih = dir ? xr : xf;
  const float* W = whh + dir * 600 * 150;
  float* out = dir ? ro : fo;
  __shared__ float h[152];
  __shared__ float gates[600];
  int tid = threadIdx.x;
  for (int u = tid; u < 150; u += 320) h[u] = 0.f;
  float creg = 0.f;
  __syncthreads();
  for (int t = 0; t < 50; t++){
    const float* xrow = xih + (b * 50 + t) * 600;
    #pragma unroll
    for (int k = 0; k < 2; k++){
      int g = k * 320 + tid;
      if (g < 600){
        const float* wr = W + g * 150;
        float sum = 0.f;
        #pragma unroll 5
        for (int u = 0; u < 150; u += 2){
          const float2 w2 = *(const float2*)(wr + u);
          sum += h[u] * w2.x + h[u + 1] * w2.y;
        }
        gates[g] = xrow[g] + sum;
      }
    }
    __syncthreads();
    if (tid < 150){
      float ig = sigm(gates[tid]);
      float fg = sigm(gates[150 + tid]);
      float gg = tanhf(gates[300 + tid]);
      float og = sigm(gates[450 + tid]);
      creg = fg * creg + ig * gg;
      float hn = og * tanhf(creg);
      h[tid] = hn;
      out[(b * 50 + t) * 150 + tid] = hn;
    }
    __syncthreads();
  }
}

// ---------------- node feature assembly [17600 x 300] -----------------------
__global__ void gcnk_nodes_in(const int* __restrict__ x, const float* __restrict__ tab,
                              const float* __restrict__ cnnf, const float* __restrict__ lstmf,
                              float* __restrict__ out){
  int idx = blockIdx.x * 256 + threadIdx.x;
  if (idx >= NNODES * 300) return;
  int nrow = idx / 300, d = idx - nrow * 300;
  int b = nrow / 550, j = nrow - b * 550;
  float v;
  if (j < 500) v = tab[x[b * 500 + j] * 300 + d];
  else {
    int r = b * 50 + (j - 500);
    v = (d < 150) ? cnnf[r * 150 + d] : lstmf[r * 150 + d - 150];
  }
  out[idx] = v;
}

// ---------------- GCN: CSR build (counting sort by dst) ---------------------
__global__ void gcnk_hist(const int* __restrict__ ei, int* __restrict__ ecnt){
  int e = blockIdx.x * 256 + threadIdx.x;
  if (e < EDGES) atomicAdd(&ecnt[ei[EDGES + e]], 1);
}

__global__ __launch_bounds__(1024)
void gcnk_scan(const int* __restrict__ ecnt, int* __restrict__ eoff,
               int* __restrict__ ecur){
  __shared__ int buf[1024];
  int tid = threadIdx.x;
  int running = 0;
  for (int c = 0; c < 18; c++){
    int i = c * 1024 + tid;
    int v = (i < NNODES) ? ecnt[i] : 0;
    buf[tid] = v;
    __syncthreads();
    for (int s = 1; s < 1024; s <<= 1){
      int t2 = (tid >= s) ? buf[tid - s] : 0;
      __syncthreads();
      buf[tid] += t2;
      __syncthreads();
    }
    int excl = running + buf[tid] - v;
    int tot = buf[1023];
    if (i < NNODES){ eoff[i] = excl; ecur[i] = excl; }
    running += tot;
    __syncthreads();
  }
}

__global__ void gcnk_scatter(const int* __restrict__ ei, int* __restrict__ ecur,
                             int* __restrict__ esrc){
  int e = blockIdx.x * 256 + threadIdx.x;
  if (e < EDGES){
    int d = ei[EDGES + e];
    int p = atomicAdd(&ecur[d], 1);
    esrc[p] = ei[e];
  }
}

__global__ void gcnk_dis2(const int* __restrict__ ecnt, float* __restrict__ dis){
  int i = blockIdx.x * 256 + threadIdx.x;
  if (i < NNODES) dis[i] = rsqrtf((float)(ecnt[i] + 1));  // +1 self-loop; always > 0
}

// ---------------- GCN aggregation: CSR gather, no atomics -------------------
// agg[d][c] = (sum_{s in N(d)} xw[s][c]*dis[s] + xw[d][c]*dis[d]) * dis[d]
__global__ __launch_bounds__(128)
void gcnk_aggcsr(const int* __restrict__ eoff, const int* __restrict__ ecnt,
                 const int* __restrict__ esrc, const float* __restrict__ dis,
                 const float* __restrict__ xw, float* __restrict__ agg){
  int d = blockIdx.x, t = threadIdx.x;
  float dd = dis[d];
  const float* xd = xw + (size_t)d * 150;
  float a0 = xd[t] * dd;
  float a1 = (t < 22) ? xd[128 + t] * dd : 0.f;
  int beg = eoff[d], end = beg + ecnt[d];
  for (int j = beg; j < end; j++){
    int s = esrc[j];
    float ds = dis[s];
    const float* xs = xw + (size_t)s * 150;
    a0 += xs[t] * ds;
    if (t < 22) a1 += xs[128 + t] * ds;
  }
  agg[(size_t)d * 150 + t] = a0 * dd;
  if (t < 22) agg[(size_t)d * 150 + 128 + t] = a1 * dd;
}

__global__ void gcnk_elu(float* __restrict__ h, const float* __restrict__ agg,
                         const float* __restrict__ bias){
  int idx = blockIdx.x * 256 + threadIdx.x;
  if (idx >= NNODES * 150) return;
  int c = idx % 150;
  float v = agg[idx] + bias[c];
  h[idx] = (v > 0.f) ? v : expm1f(v);
}

__global__ void gcnk_out0(float* __restrict__ out, const float* __restrict__ agg,
                          const float* __restrict__ bias){
  int idx = blockIdx.x * 256 + threadIdx.x;
  if (idx >= NNODES * 150) return;
  int c = idx % 150;
  out[idx] = agg[idx] + bias[c];
}

// ============================================================================
extern "C" void kernel_launch(void* const* d_in, const int* in_sizes, int n_in,
                              void* d_out, int out_size, void* d_ws, size_t ws_size,
                              hipStream_t stream){
  (void)in_sizes; (void)n_in; (void)out_size; (void)ws_size;

  char* wsb = (char*)d_ws;
  size_t off = 0;
  auto alloc = [&](size_t bytes) -> void* {
    void* p = wsb + off;
    off = (off + bytes + 255) & ~(size_t)255;
    return p;
  };
  float* pos_tab  = (float*)alloc(513 * 300 * 4);
  int*   sentlen  = (int*)alloc(1600 * 4);
  int*   glen     = (int*)alloc(32 * 4);
  int*   rowmap   = (int*)alloc(1600 * 4);
  float* ngram    = (float*)alloc(1600 * 300 * 4);   // uint-atomics then read as float
  float* cnn_feat = (float*)alloc(1600 * 150 * 4);
  float* cnn_rev  = (float*)alloc(1600 * 150 * 4);
  float* xih_f    = (float*)alloc(1600 * 600 * 4);
  float* xih_r    = (float*)alloc(1600 * 600 * 4);
  float* f0       = (float*)alloc(1600 * 150 * 4);
  float* r0       = (float*)alloc(1600 * 150 * 4);
  float* f1       = (float*)alloc(1600 * 150 * 4);
  float* r1       = (float*)alloc(1600 * 150 * 4);
  float* h1       = (float*)alloc(1600 * 300 * 4);
  float* h1rev    = (float*)alloc(1600 * 300 * 4);
  float* hm       = (float*)alloc(1600 * 300 * 4);
  float* lstm_ft  = (float*)alloc(1600 * 150 * 4);
  float* nodes_in = (float*)alloc((size_t)NNODES * 300 * 4);
  float* nodes    = (float*)alloc((size_t)NNODES * 150 * 4);
  float* dis      = (float*)alloc(NNODES * 4);
  float* xw       = (float*)alloc((size_t)NNODES * 150 * 4);
  float* agg      = (float*)alloc((size_t)NNODES * 150 * 4);
  _Float16* ench  = (_Float16*)alloc((size_t)MPAD * 300 * 2);
  _Float16* vh    = (_Float16*)alloc(405000 * 2);
  int*   ecnt     = (int*)alloc(NNODES * 4);
  int*   eoff     = (int*)alloc(NNODES * 4);
  int*   ecur     = (int*)alloc(NNODES * 4);
  int*   esrc     = (int*)alloc(EDGES * 4);

  const int*   x   = (const int*)d_in[0];
  const int*   sx  = (const int*)d_in[1];
  const int*   ei  = (const int*)d_in[2];
  const float* tab = (const float*)d_in[3];
  const float *cw[6], *cb[6];
  for (int h = 0; h < 6; h++){ cw[h] = (const float*)d_in[4 + 2 * h]; cb[h] = (const float*)d_in[5 + 2 * h]; }
  const float* cnnw = (const float*)d_in[16]; const float* cnnb = (const float*)d_in[17];
  const float* wih0 = (const float*)d_in[18]; const float* whh0 = (const float*)d_in[19];
  const float* bih0 = (const float*)d_in[20]; const float* bhh0 = (const float*)d_in[21];
  const float* wih1 = (const float*)d_in[22]; const float* whh1 = (const float*)d_in[23];
  const float* bih1 = (const float*)d_in[24]; const float* bhh1 = (const float*)d_in[25];
  const float* lpw  = (const float*)d_in[26]; const float* lpb  = (const float*)d_in[27];
  const float* g0w  = (const float*)d_in[28]; const float* g0b  = (const float*)d_in[29];
  const float* g1w  = (const float*)d_in[30]; const float* g1b  = (const float*)d_in[31];
  const float* g2w  = (const float*)d_in[32]; const float* g2b  = (const float*)d_in[33];

  float* out0 = (float*)d_out;
  float4* out1 = (float4*)((float*)d_out + OUT0SZ);

  auto gemm = [&](const float* A, const float* W, const float* b1, const float* b2,
                  float* C, int M, int N, int K){
    dim3 g((M + 31) / 32, (N + 63) / 64);
    gcnk_gemm<<<g, 256, 0, stream>>>(A, W, b1, b2, C, M, N, K);
  };

  // ---- pipeline ----
  gcnk_postab<<<602, 256, 0, stream>>>(pos_tab);
  gcnk_prep<<<7, 256, 0, stream>>>(sx, sentlen, glen);
  gcnk_rowmap<<<7, 256, 0, stream>>>(glen, rowmap);
  gcnk_embw<<<4688, 256, 0, stream>>>(x, tab, out1);

  // conv as implicit-im2col fp16 GEMM
  gcnk_zeroi<<<1875, 256, 0, stream>>>((unsigned int*)ngram, 1600 * 300);
  gcnk_ench<<<(MPAD * 300 + 255) / 256, 256, 0, stream>>>(sx, tab, pos_tab, sentlen, ench);
  gcnk_wpack<<<1583, 256, 0, stream>>>(cw[0], cw[1], cw[2], cw[3], cw[4], cw[5], vh);
  {
    const int voff[6] = {0, 30000, 75000, 135000, 210000, 300000};
    for (int h = 0; h < 6; h++){
      int H = h + 2;
      gcnk_convgemm<<<500, 256, 0, stream>>>((const h2*)ench, (const h2*)(vh + voff[h]),
                                             cb[h], (unsigned int*)ngram, 300 * H, H);
    }
  }
  gcnk_addpos<<<1875, 256, 0, stream>>>(ngram, pos_tab);
  gemm(ngram, cnnw, cnnb, nullptr, cnn_feat, 1600, 150, 300);

  // BiLSTM layer 0
  gcnk_permute150<<<938, 256, 0, stream>>>(cnn_rev, cnn_feat, rowmap);
  gemm(cnn_feat, wih0,             bih0,       bhh0,       xih_f, 1600, 600, 150);
  gemm(cnn_rev,  wih0 + 600 * 150, bih0 + 600, bhh0 + 600, xih_r, 1600, 600, 150);
  gcnk_lstm<<<64, 320, 0, stream>>>(xih_f, xih_r, whh0, f0, r0);

  // BiLSTM layer 1
  gcnk_concat<<<1875, 256, 0, stream>>>(h1,    f0, r0, nullptr, rowmap, glen, 0);
  gcnk_concat<<<1875, 256, 0, stream>>>(h1rev, f0, r0, rowmap, nullptr, glen, 0);
  gemm(h1,    wih1,             bih1,       bhh1,       xih_f, 1600, 600, 300);
  gemm(h1rev, wih1 + 600 * 300, bih1 + 600, bhh1 + 600, xih_r, 1600, 600, 300);
  gcnk_lstm<<<64, 320, 0, stream>>>(xih_f, xih_r, whh1, f1, r1);

  // masked projection
  gcnk_concat<<<1875, 256, 0, stream>>>(hm, f1, r1, nullptr, rowmap, glen, 1);
  gemm(hm, lpw, lpb, nullptr, lstm_ft, 1600, 150, 300);

  // node features + gc0
  gcnk_nodes_in<<<20625, 256, 0, stream>>>(x, tab, cnn_feat, lstm_ft, nodes_in);
  gemm(nodes_in, g0w, g0b, nullptr, nodes, NNODES, 150, 300);

  // CSR build (once, reused by both GCN layers)
  gcnk_zeroi<<<69, 256, 0, stream>>>((unsigned int*)ecnt, NNODES);
  gcnk_hist<<<2200, 256, 0, stream>>>(ei, ecnt);
  gcnk_scan<<<1, 1024, 0, stream>>>(ecnt, eoff, ecur);
  gcnk_scatter<<<2200, 256, 0, stream>>>(ei, ecur, esrc);
  gcnk_dis2<<<69, 256, 0, stream>>>(ecnt, dis);

  // gc1 + elu
  gemm(nodes, g1w, nullptr, nullptr, xw, NNODES, 150, 150);
  gcnk_aggcsr<<<NNODES, 128, 0, stream>>>(eoff, ecnt, esrc, dis, xw, agg);
  gcnk_elu<<<10313, 256, 0, stream>>>(nodes, agg, g1b);

  // gc2 -> output 0
  gemm(nodes, g2w, nullptr, nullptr, xw, NNODES, 150, 150);
  gcnk_aggcsr<<<NNODES, 128, 0, stream>>>(eoff, ecnt, esrc, dis, xw, agg);
  gcnk_out0<<<10313, 256, 0, stream>>>(out0, agg, g2b);
}

// Round 4
// 1877.667 us; speedup vs baseline: 2.2384x; 1.3236x over previous
//
#include <hip/hip_runtime.h>
#include <stdint.h>
#include <math.h>

// Problem constants (match reference)
#define EDGES 563200
#define NNODES 17600    // B*(NW+NS)
#define OUT0SZ 2640000  // 17600*150
#define MROWS 64000     // 1600 sentences * 40 positions
#define MPAD  64016     // + zero pad rows for window overhang

typedef _Float16 h2 __attribute__((ext_vector_type(2)));

__device__ __forceinline__ float sigm(float x){ return 1.f / (1.f + expf(-x)); }

__device__ __forceinline__ float fdot2_(h2 a, h2 b, float c){
#if __has_builtin(__builtin_amdgcn_fdot2)
  return __builtin_amdgcn_fdot2(a, b, c, false);
#else
  return c + (float)a.x * (float)b.x + (float)a.y * (float)b.y;
#endif
}

// ---------------- POS table (numpy float64 sinusoid, row 0 zeroed) ----------
__global__ void gcnk_postab(float* __restrict__ pos){
  int idx = blockIdx.x * 256 + threadIdx.x;
  if (idx >= 513 * 300) return;
  int p = idx / 300, i = idx - p * 300;
  float v = 0.f;
  if (p != 0){
    double expo = (double)(2 * (i / 2)) / 300.0;
    double ang = (double)p / pow(10000.0, expo);
    v = (float)((i & 1) ? cos(ang) : sin(ang));
  }
  pos[idx] = v;
}

// ---------------- sentlen + glen --------------------------------------------
__global__ void gcnk_prep(const int* __restrict__ sx, int* __restrict__ sentlen,
                          int* __restrict__ glen){
  int tid = blockIdx.x * 256 + threadIdx.x;
  if (tid < 1600){
    int c = 0;
    for (int j = 0; j < 40; j++) c += (sx[tid * 40 + j] != 0);
    sentlen[tid] = c;
  } else if (tid < 1632){
    int b = tid - 1600, c = 0;
    for (int s = 0; s < 50; s++) c += (sx[b * 2000 + s * 40] != 0);
    glen[b] = c;
  }
}

__global__ void gcnk_rowmap(const int* __restrict__ glen, int* __restrict__ rowmap){
  int i = blockIdx.x * 256 + threadIdx.x;
  if (i >= 1600) return;
  int b = i / 50, t = i - b * 50, g = glen[b];
  rowmap[i] = b * 50 + ((t < g) ? (g - 1 - t) : t);
}

// ---------------- emb_words output ------------------------------------------
__global__ void gcnk_embw(const int* __restrict__ x, const float* __restrict__ tab,
                          float4* __restrict__ out){
  int idx = blockIdx.x * 256 + threadIdx.x;
  if (idx >= 16000 * 75) return;
  int row = idx / 75, q = idx - row * 75;
  const float4* t = (const float4*)tab;
  out[idx] = t[x[row] * 75 + q];
}

// ---------------- generic zero ----------------------------------------------
__global__ void gcnk_zeroi(unsigned int* __restrict__ p, int n){
  int i = blockIdx.x * 256 + threadIdx.x;
  if (i < n) p[i] = 0u;
}

// ---------------- enc (fp16): enc[m][d] = tab[tok]+pos, pad rows zero -------
__global__ void gcnk_ench(const int* __restrict__ sx, const float* __restrict__ tab,
                          const float* __restrict__ pos, const int* __restrict__ sentlen,
                          _Float16* __restrict__ ench){
  int idx = blockIdx.x * 256 + threadIdx.x;
  if (idx >= MPAD * 300) return;
  int row = idx / 300, d = idx - row * 300;
  float v = 0.f;
  if (row < MROWS){
    int n = row / 40, l = row - n * 40;
    int tok = sx[n * 40 + l];
    int p = (l < sentlen[n]) ? (l + 1) : 0;
    v = tab[tok * 300 + d] + pos[p * 300 + d];
  }
  ench[idx] = (_Float16)v;
}

// ---------------- conv weights -> fp16, concatenated per head ---------------
__global__ void gcnk_wpack(const float* w2, const float* w3, const float* w4,
                           const float* w5, const float* w6, const float* w7,
                           _Float16* __restrict__ vh){
  int idx = blockIdx.x * 256 + threadIdx.x;
  if (idx >= 405000) return;
  const float* src; int off;
  if      (idx < 30000) { src = w2; off = 0; }
  else if (idx < 75000) { src = w3; off = 30000; }
  else if (idx < 135000){ src = w4; off = 75000; }
  else if (idx < 210000){ src = w5; off = 135000; }
  else if (idx < 300000){ src = w6; off = 210000; }
  else                  { src = w7; off = 300000; }
  vh[idx] = (_Float16)src[idx - off];
}

// ---------------- lstm whh -> fp16, rows padded 150 -> 152 ------------------
__global__ void gcnk_whhpack(const float* __restrict__ whh, _Float16* __restrict__ wpad){
  int idx = blockIdx.x * 256 + threadIdx.x;
  if (idx >= 1200 * 152) return;         // 2 dirs * 600 gates * 152
  int row = idx / 152, col = idx - row * 152;
  wpad[idx] = (col < 150) ? (_Float16)whh[row * 150 + col] : (_Float16)0.f;
}

// ---------------- conv as implicit-im2col GEMM (fp16 in, fp32 acc) ----------
__global__ __launch_bounds__(256)
void gcnk_convgemm(const h2* __restrict__ A2, const h2* __restrict__ B2,
                   const float* __restrict__ bias, unsigned int* __restrict__ ngram_u,
                   int K, int H){
  __shared__ float smem[128 * 65];           // 33.3 KB
  h2* As = (h2*)smem;                         // [32][128]
  h2* Bs = (h2*)(smem + 4096);                // [32][64]
  const int tid = threadIdx.x;
  const int m0 = blockIdx.x * 128;
  const int tn = tid & 15, tm = tid >> 4;     // micro-tile 8(m) x 4(n)
  const int K2 = K >> 1;
  const int nchunks = (K + 63) / 64;
  const int ar = tid & 127, ahi = tid >> 7;
  const int br = tid & 63,  bhi = tid >> 6;
  float acc[8][4] = {};
  for (int ch = 0; ch < nchunks; ch++){
    int kc2 = ch * 32;
    {
      const h2* g = A2 + (size_t)(m0 + ar) * 150 + kc2 + ahi * 16;
      #pragma unroll
      for (int j = 0; j < 16; j++) As[(ahi * 16 + j) * 128 + ar] = g[j];
    }
    {
      int c2 = kc2 + bhi * 8;
      const h2* g = B2 + (size_t)br * K2 + c2;
      #pragma unroll
      for (int j = 0; j < 8; j++){
        h2 v; v.x = (_Float16)0; v.y = (_Float16)0;
        if (br < 50 && (c2 + j) < K2) v = g[j];
        Bs[(bhi * 8 + j) * 64 + br] = v;
      }
    }
    __syncthreads();
    #pragma unroll
    for (int kk = 0; kk < 32; kk++){
      h2 a[8], b[4];
      #pragma unroll
      for (int i = 0; i < 8; i++) a[i] = As[kk * 128 + tm * 8 + i];
      #pragma unroll
      for (int j = 0; j < 4; j++) b[j] = Bs[kk * 64 + tn * 4 + j];
      #pragma unroll
      for (int i = 0; i < 8; i++)
        #pragma unroll
        for (int j = 0; j < 4; j++)
          acc[i][j] = fdot2_(a[i], b[j], acc[i][j]);
    }
    __syncthreads();
  }
  #pragma unroll
  for (int i = 0; i < 8; i++)
    #pragma unroll
    for (int j = 0; j < 4; j++)
      smem[(tm * 8 + i) * 65 + tn * 4 + j] = acc[i][j];
  __syncthreads();
  if (tid < 250){
    int nl = tid / 50, o = tid - nl * 50;
    int n = m0 / 40 + nl;
    if (n < 1600){
      int lh = 41 - H;
      int l_lo = m0 - n * 40; if (l_lo < 0) l_lo = 0;
      int l_hi = m0 + 128 - n * 40; if (l_hi > lh) l_hi = lh;
      if (l_lo < l_hi){
        float bv = bias[o];
        float vmax = 0.f;
        for (int l = l_lo; l < l_hi; l++){
          float v = smem[(n * 40 + l - m0) * 65 + o] + bv;
          vmax = fmaxf(vmax, v);
        }
        atomicMax(ngram_u + n * 300 + (H - 2) * 50 + o, __float_as_uint(vmax));
      }
    }
  }
}

// ngram += POS_TAB[n % 50]
__global__ void gcnk_addpos(float* __restrict__ ngram, const float* __restrict__ pos){
  int idx = blockIdx.x * 256 + threadIdx.x;
  if (idx >= 1600 * 300) return;
  int row = idx / 300, d = idx - row * 300;
  ngram[idx] += pos[(row % 50) * 300 + d];
}

// ---------------- generic fp32 GEMM: C[M,N] = A[M,K] * W[N,K]^T + b1 + b2 ---
__global__ __launch_bounds__(256)
void gcnk_gemm(const float* __restrict__ A, const float* __restrict__ Wt,
               const float* __restrict__ bias1, const float* __restrict__ bias2,
               float* __restrict__ C, int M, int N, int K){
  __shared__ float As[32][34];
  __shared__ float Ws[32][68];
  const int tid = threadIdx.x;
  const int m0 = blockIdx.x * 32, n0 = blockIdx.y * 64;
  const int i = tid >> 4, j = tid & 15;
  float acc[2][4] = {{0.f,0.f,0.f,0.f},{0.f,0.f,0.f,0.f}};
  for (int kc = 0; kc < K; kc += 32){
    #pragma unroll
    for (int t = 0; t < 4; t++){
      int idx = tid + t * 256;
      int r = idx >> 5, c = idx & 31;
      int gm = m0 + r, gk = kc + c;
      As[c][r] = (gm < M && gk < K) ? A[gm * K + gk] : 0.f;
    }
    #pragma unroll
    for (int t = 0; t < 8; t++){
      int idx = tid + t * 256;
      int r = idx & 63, c = idx >> 6;
      int gn = n0 + r, gk = kc + c;
      Ws[c][r] = (gn < N && gk < K) ? Wt[gn * K + gk] : 0.f;
    }
    __syncthreads();
    #pragma unroll
    for (int kk = 0; kk < 32; kk++){
      const float2 a = *(const float2*)&As[kk][2 * i];
      const float4 w = *(const float4*)&Ws[kk][4 * j];
      acc[0][0] += a.x * w.x; acc[0][1] += a.x * w.y; acc[0][2] += a.x * w.z; acc[0][3] += a.x * w.w;
      acc[1][0] += a.y * w.x; acc[1][1] += a.y * w.y; acc[1][2] += a.y * w.z; acc[1][3] += a.y * w.w;
    }
    __syncthreads();
  }
  #pragma unroll
  for (int r = 0; r < 2; r++){
    int gm = m0 + 2 * i + r;
    if (gm >= M) continue;
    #pragma unroll
    for (int cc = 0; cc < 4; cc++){
      int gn = n0 + 4 * j + cc;
      if (gn >= N) continue;
      float v = acc[r][cc];
      if (bias1) v += bias1[gn];
      if (bias2) v += bias2[gn];
      C[gm * N + gn] = v;
    }
  }
}

// ---------------- row permute / concat --------------------------------------
__global__ void gcnk_permute150(float* __restrict__ dst, const float* __restrict__ src,
                                const int* __restrict__ map){
  int idx = blockIdx.x * 256 + threadIdx.x;
  if (idx >= 1600 * 150) return;
  int row = idx / 150, d = idx - row * 150;
  dst[idx] = src[map[row] * 150 + d];
}

__global__ void gcnk_concat(float* __restrict__ dst, const float* __restrict__ A,
                            const float* __restrict__ Bs, const int* __restrict__ mapA,
                            const int* __restrict__ mapB, const int* __restrict__ glen,
                            int usemask){
  int idx = blockIdx.x * 256 + threadIdx.x;
  if (idx >= 1600 * 300) return;
  int row = idx / 300, d = idx - row * 300;
  int b = row / 50, t = row - b * 50;
  float v;
  if (d < 150){ int r = mapA ? mapA[row] : row; v = A[r * 150 + d]; }
  else        { int r = mapB ? mapB[row] : row; v = Bs[r * 150 + d - 150]; }
  if (usemask && t >= glen[b]) v = 0.f;
  dst[idx] = v;
}

// ---------------- LSTM recurrence: weights in VGPRs, h fp16 in LDS ----------
// wpad: fp16 [2 dir][600 gate][152] (cols 150,151 zero).
// Thread g<600 owns gate g (76 h2 weight regs); threads u<150 do the epilogue.
__global__ __launch_bounds__(640)
void gcnk_lstm(const float* __restrict__ xf, const float* __restrict__ xr,
               const _Float16* __restrict__ wpad, float* __restrict__ fo,
               float* __restrict__ ro){
  int b = blockIdx.x >> 1, dir = blockIdx.x & 1;
  const float* xih = dir ? xr : xf;
  float* out = dir ? ro : fo;
  __shared__ __align__(16) _Float16 hh[160];   // h as fp16, zero-padded
  __shared__ float gates[600];
  const int tid = threadIdx.x;

  // load my gate's weight row into registers
  h2 w[76];
  if (tid < 600){
    const h2* wrow = (const h2*)(wpad + ((size_t)dir * 600 + tid) * 152);
    #pragma unroll
    for (int j = 0; j < 76; j++) w[j] = wrow[j];
  }
  for (int u = tid; u < 160; u += 640) hh[u] = (_Float16)0.f;
  float creg = 0.f;
  __syncthreads();

  for (int t = 0; t < 50; t++){
    if (tid < 600){
      float acc = xih[(b * 50 + t) * 600 + tid];
      #pragma unroll
      for (int j = 0; j < 19; j++){
        union { float4 f; h2 h[4]; } u;
        u.f = *(const float4*)(hh + j * 8);
        acc = fdot2_(w[4 * j + 0], u.h[0], acc);
        acc = fdot2_(w[4 * j + 1], u.h[1], acc);
        acc = fdot2_(w[4 * j + 2], u.h[2], acc);
        acc = fdot2_(w[4 * j + 3], u.h[3], acc);
      }
      gates[tid] = acc;
    }
    __syncthreads();
    if (tid < 150){
      float ig = sigm(gates[tid]);
      float fg = sigm(gates[150 + tid]);
      float gg = tanhf(gates[300 + tid]);
      float og = sigm(gates[450 + tid]);
      creg = fg * creg + ig * gg;
      float hn = og * tanhf(creg);
      hh[tid] = (_Float16)hn;
      out[(b * 50 + t) * 150 + tid] = hn;
    }
    __syncthreads();
  }
}

// ---------------- node feature assembly [17600 x 300] -----------------------
__global__ void gcnk_nodes_in(const int* __restrict__ x, const float* __restrict__ tab,
                              const float* __restrict__ cnnf, const float* __restrict__ lstmf,
                              float* __restrict__ out){
  int idx = blockIdx.x * 256 + threadIdx.x;
  if (idx >= NNODES * 300) return;
  int nrow = idx / 300, d = idx - nrow * 300;
  int b = nrow / 550, j = nrow - b * 550;
  float v;
  if (j < 500) v = tab[x[b * 500 + j] * 300 + d];
  else {
    int r = b * 50 + (j - 500);
    v = (d < 150) ? cnnf[r * 150 + d] : lstmf[r * 150 + d - 150];
  }
  out[idx] = v;
}

// ---------------- GCN: CSR build (counting sort by dst) ---------------------
__global__ void gcnk_hist(const int* __restrict__ ei, int* __restrict__ ecnt){
  int e = blockIdx.x * 256 + threadIdx.x;
  if (e < EDGES) atomicAdd(&ecnt[ei[EDGES + e]], 1);
}

__global__ __launch_bounds__(1024)
void gcnk_scan(const int* __restrict__ ecnt, int* __restrict__ eoff,
               int* __restrict__ ecur){
  __shared__ int buf[1024];
  int tid = threadIdx.x;
  int running = 0;
  for (int c = 0; c < 18; c++){
    int i = c * 1024 + tid;
    int v = (i < NNODES) ? ecnt[i] : 0;
    buf[tid] = v;
    __syncthreads();
    for (int s = 1; s < 1024; s <<= 1){
      int t2 = (tid >= s) ? buf[tid - s] : 0;
      __syncthreads();
      buf[tid] += t2;
      __syncthreads();
    }
    int excl = running + buf[tid] - v;
    int tot = buf[1023];
    if (i < NNODES){ eoff[i] = excl; ecur[i] = excl; }
    running += tot;
    __syncthreads();
  }
}

__global__ void gcnk_scatter(const int* __restrict__ ei, int* __restrict__ ecur,
                             int* __restrict__ esrc){
  int e = blockIdx.x * 256 + threadIdx.x;
  if (e < EDGES){
    int d = ei[EDGES + e];
    int p = atomicAdd(&ecur[d], 1);
    esrc[p] = ei[e];
  }
}

__global__ void gcnk_dis2(const int* __restrict__ ecnt, float* __restrict__ dis){
  int i = blockIdx.x * 256 + threadIdx.x;
  if (i < NNODES) dis[i] = rsqrtf((float)(ecnt[i] + 1));
}

// ---------------- GCN aggregation: CSR gather, no atomics -------------------
__global__ __launch_bounds__(128)
void gcnk_aggcsr(const int* __restrict__ eoff, const int* __restrict__ ecnt,
                 const int* __restrict__ esrc, const float* __restrict__ dis,
                 const float* __restrict__ xw, float* __restrict__ agg){
  int d = blockIdx.x, t = threadIdx.x;
  float dd = dis[d];
  const float* xd = xw + (size_t)d * 150;
  float a0 = xd[t] * dd;
  float a1 = (t < 22) ? xd[128 + t] * dd : 0.f;
  int beg = eoff[d], end = beg + ecnt[d];
  for (int j = beg; j < end; j++){
    int s = esrc[j];
    float ds = dis[s];
    const float* xs = xw + (size_t)s * 150;
    a0 += xs[t] * ds;
    if (t < 22) a1 += xs[128 + t] * ds;
  }
  agg[(size_t)d * 150 + t] = a0 * dd;
  if (t < 22) agg[(size_t)d * 150 + 128 + t] = a1 * dd;
}

__global__ void gcnk_elu(float* __restrict__ h, const float* __restrict__ agg,
                         const float* __restrict__ bias){
  int idx = blockIdx.x * 256 + threadIdx.x;
  if (idx >= NNODES * 150) return;
  int c = idx % 150;
  float v = agg[idx] + bias[c];
  h[idx] = (v > 0.f) ? v : expm1f(v);
}

__global__ void gcnk_out0(float* __restrict__ out, const float* __restrict__ agg,
                          const float* __restrict__ bias){
  int idx = blockIdx.x * 256 + threadIdx.x;
  if (idx >= NNODES * 150) return;
  int c = idx % 150;
  out[idx] = agg[idx] + bias[c];
}

// ============================================================================
extern "C" void kernel_launch(void* const* d_in, const int* in_sizes, int n_in,
                              void* d_out, int out_size, void* d_ws, size_t ws_size,
                              hipStream_t stream){
  (void)in_sizes; (void)n_in; (void)out_size; (void)ws_size;

  char* wsb = (char*)d_ws;
  size_t off = 0;
  auto alloc = [&](size_t bytes) -> void* {
    void* p = wsb + off;
    off = (off + bytes + 255) & ~(size_t)255;
    return p;
  };
  float* pos_tab  = (float*)alloc(513 * 300 * 4);
  int*   sentlen  = (int*)alloc(1600 * 4);
  int*   glen     = (int*)alloc(32 * 4);
  int*   rowmap   = (int*)alloc(1600 * 4);
  float* ngram    = (float*)alloc(1600 * 300 * 4);
  float* cnn_feat = (float*)alloc(1600 * 150 * 4);
  float* cnn_rev  = (float*)alloc(1600 * 150 * 4);
  float* xih_f    = (float*)alloc(1600 * 600 * 4);
  float* xih_r    = (float*)alloc(1600 * 600 * 4);
  float* f0       = (float*)alloc(1600 * 150 * 4);
  float* r0       = (float*)alloc(1600 * 150 * 4);
  float* f1       = (float*)alloc(1600 * 150 * 4);
  float* r1       = (float*)alloc(1600 * 150 * 4);
  float* h1       = (float*)alloc(1600 * 300 * 4);
  float* h1rev    = (float*)alloc(1600 * 300 * 4);
  float* hm       = (float*)alloc(1600 * 300 * 4);
  float* lstm_ft  = (float*)alloc(1600 * 150 * 4);
  float* nodes_in = (float*)alloc((size_t)NNODES * 300 * 4);
  float* nodes    = (float*)alloc((size_t)NNODES * 150 * 4);
  float* dis      = (float*)alloc(NNODES * 4);
  float* xw       = (float*)alloc((size_t)NNODES * 150 * 4);
  float* agg      = (float*)alloc((size_t)NNODES * 150 * 4);
  _Float16* ench  = (_Float16*)alloc((size_t)MPAD * 300 * 2);
  _Float16* vh    = (_Float16*)alloc(405000 * 2);
  _Float16* wpad0 = (_Float16*)alloc(1200 * 152 * 2);
  _Float16* wpad1 = (_Float16*)alloc(1200 * 152 * 2);
  int*   ecnt     = (int*)alloc(NNODES * 4);
  int*   eoff     = (int*)alloc(NNODES * 4);
  int*   ecur     = (int*)alloc(NNODES * 4);
  int*   esrc     = (int*)alloc(EDGES * 4);

  const int*   x   = (const int*)d_in[0];
  const int*   sx  = (const int*)d_in[1];
  const int*   ei  = (const int*)d_in[2];
  const float* tab = (const float*)d_in[3];
  const float *cw[6], *cb[6];
  for (int h = 0; h < 6; h++){ cw[h] = (const float*)d_in[4 + 2 * h]; cb[h] = (const float*)d_in[5 + 2 * h]; }
  const float* cnnw = (const float*)d_in[16]; const float* cnnb = (const float*)d_in[17];
  const float* wih0 = (const float*)d_in[18]; const float* whh0 = (const float*)d_in[19];
  const float* bih0 = (const float*)d_in[20]; const float* bhh0 = (const float*)d_in[21];
  const float* wih1 = (const float*)d_in[22]; const float* whh1 = (const float*)d_in[23];
  const float* bih1 = (const float*)d_in[24]; const float* bhh1 = (const float*)d_in[25];
  const float* lpw  = (const float*)d_in[26]; const float* lpb  = (const float*)d_in[27];
  const float* g0w  = (const float*)d_in[28]; const float* g0b  = (const float*)d_in[29];
  const float* g1w  = (const float*)d_in[30]; const float* g1b  = (const float*)d_in[31];
  const float* g2w  = (const float*)d_in[32]; const float* g2b  = (const float*)d_in[33];

  float* out0 = (float*)d_out;
  float4* out1 = (float4*)((float*)d_out + OUT0SZ);

  auto gemm = [&](const float* A, const float* W, const float* b1, const float* b2,
                  float* C, int M, int N, int K){
    dim3 g((M + 31) / 32, (N + 63) / 64);
    gcnk_gemm<<<g, 256, 0, stream>>>(A, W, b1, b2, C, M, N, K);
  };

  // ---- pipeline ----
  gcnk_postab<<<602, 256, 0, stream>>>(pos_tab);
  gcnk_prep<<<7, 256, 0, stream>>>(sx, sentlen, glen);
  gcnk_rowmap<<<7, 256, 0, stream>>>(glen, rowmap);
  gcnk_embw<<<4688, 256, 0, stream>>>(x, tab, out1);

  // conv as implicit-im2col fp16 GEMM
  gcnk_zeroi<<<1875, 256, 0, stream>>>((unsigned int*)ngram, 1600 * 300);
  gcnk_ench<<<(MPAD * 300 + 255) / 256, 256, 0, stream>>>(sx, tab, pos_tab, sentlen, ench);
  gcnk_wpack<<<1583, 256, 0, stream>>>(cw[0], cw[1], cw[2], cw[3], cw[4], cw[5], vh);
  gcnk_whhpack<<<713, 256, 0, stream>>>(whh0, wpad0);
  gcnk_whhpack<<<713, 256, 0, stream>>>(whh1, wpad1);
  {
    const int voff[6] = {0, 30000, 75000, 135000, 210000, 300000};
    for (int h = 0; h < 6; h++){
      int H = h + 2;
      gcnk_convgemm<<<500, 256, 0, stream>>>((const h2*)ench, (const h2*)(vh + voff[h]),
                                             cb[h], (unsigned int*)ngram, 300 * H, H);
    }
  }
  gcnk_addpos<<<1875, 256, 0, stream>>>(ngram, pos_tab);
  gemm(ngram, cnnw, cnnb, nullptr, cnn_feat, 1600, 150, 300);

  // BiLSTM layer 0
  gcnk_permute150<<<938, 256, 0, stream>>>(cnn_rev, cnn_feat, rowmap);
  gemm(cnn_feat, wih0,             bih0,       bhh0,       xih_f, 1600, 600, 150);
  gemm(cnn_rev,  wih0 + 600 * 150, bih0 + 600, bhh0 + 600, xih_r, 1600, 600, 150);
  gcnk_lstm<<<64, 640, 0, stream>>>(xih_f, xih_r, wpad0, f0, r0);

  // BiLSTM layer 1
  gcnk_concat<<<1875, 256, 0, stream>>>(h1,    f0, r0, nullptr, rowmap, glen, 0);
  gcnk_concat<<<1875, 256, 0, stream>>>(h1rev, f0, r0, rowmap, nullptr, glen, 0);
  gemm(h1,    wih1,             bih1,       bhh1,       xih_f, 1600, 600, 300);
  gemm(h1rev, wih1 + 600 * 300, bih1 + 600, bhh1 + 600, xih_r, 1600, 600, 300);
  gcnk_lstm<<<64, 640, 0, stream>>>(xih_f, xih_r, wpad1, f1, r1);

  // masked projection
  gcnk_concat<<<1875, 256, 0, stream>>>(hm, f1, r1, nullptr, rowmap, glen, 1);
  gemm(hm, lpw, lpb, nullptr, lstm_ft, 1600, 150, 300);

  // node features + gc0
  gcnk_nodes_in<<<20625, 256, 0, stream>>>(x, tab, cnn_feat, lstm_ft, nodes_in);
  gemm(nodes_in, g0w, g0b, nullptr, nodes, NNODES, 150, 300);

  // CSR build (once, reused by both GCN layers)
  gcnk_zeroi<<<69, 256, 0, stream>>>((unsigned int*)ecnt, NNODES);
  gcnk_hist<<<2200, 256, 0, stream>>>(ei, ecnt);
  gcnk_scan<<<1, 1024, 0, stream>>>(ecnt, eoff, ecur);
  gcnk_scatter<<<2200, 256, 0, stream>>>(ei, ecur, esrc);
  gcnk_dis2<<<69, 256, 0, stream>>>(ecnt, dis);

  // gc1 + elu
  gemm(nodes, g1w, nullptr, nullptr, xw, NNODES, 150, 150);
  gcnk_aggcsr<<<NNODES, 128, 0, stream>>>(eoff, ecnt, esrc, dis, xw, agg);
  gcnk_elu<<<10313, 256, 0, stream>>>(nodes, agg, g1b);

  // gc2 -> output 0
  gemm(nodes, g2w, nullptr, nullptr, xw, NNODES, 150, 150);
  gcnk_aggcsr<<<NNODES, 128, 0, stream>>>(eoff, ecnt, esrc, dis, xw, agg);
  gcnk_out0<<<10313, 256, 0, stream>>>(out0, agg, g2b);
}

// Round 5
// 1306.585 us; speedup vs baseline: 3.2168x; 1.4371x over previous
//
#include <hip/hip_runtime.h>
#include <stdint.h>
#include <math.h>

// Problem constants (match reference)
#define EDGES 563200
#define NNODES 17600    // B*(NW+NS)
#define OUT0SZ 2640000  // 17600*150
#define MROWS 64000     // 1600 sentences * 40 positions
#define MPAD  64016     // + zero pad rows for window overhang
#define KPACK 2112      // 300*7 rounded up to 32
#define NPACK 320       // 6 heads * 50 rounded to 32

typedef _Float16 h2 __attribute__((ext_vector_type(2)));
typedef _Float16 v8h __attribute__((ext_vector_type(8)));
typedef float v4f __attribute__((ext_vector_type(4)));

__device__ __forceinline__ float sigm(float x){ return 1.f / (1.f + expf(-x)); }

__device__ __forceinline__ float fdot2_(h2 a, h2 b, float c){
#if __has_builtin(__builtin_amdgcn_fdot2)
  return __builtin_amdgcn_fdot2(a, b, c, false);
#else
  return c + (float)a.x * (float)b.x + (float)a.y * (float)b.y;
#endif
}

// ---------------- POS table (numpy float64 sinusoid, row 0 zeroed) ----------
__global__ void gcnk_postab(float* __restrict__ pos){
  int idx = blockIdx.x * 256 + threadIdx.x;
  if (idx >= 513 * 300) return;
  int p = idx / 300, i = idx - p * 300;
  float v = 0.f;
  if (p != 0){
    double expo = (double)(2 * (i / 2)) / 300.0;
    double ang = (double)p / pow(10000.0, expo);
    v = (float)((i & 1) ? cos(ang) : sin(ang));
  }
  pos[idx] = v;
}

// ---------------- sentlen + glen --------------------------------------------
__global__ void gcnk_prep(const int* __restrict__ sx, int* __restrict__ sentlen,
                          int* __restrict__ glen){
  int tid = blockIdx.x * 256 + threadIdx.x;
  if (tid < 1600){
    int c = 0;
    for (int j = 0; j < 40; j++) c += (sx[tid * 40 + j] != 0);
    sentlen[tid] = c;
  } else if (tid < 1632){
    int b = tid - 1600, c = 0;
    for (int s = 0; s < 50; s++) c += (sx[b * 2000 + s * 40] != 0);
    glen[b] = c;
  }
}

__global__ void gcnk_rowmap(const int* __restrict__ glen, int* __restrict__ rowmap){
  int i = blockIdx.x * 256 + threadIdx.x;
  if (i >= 1600) return;
  int b = i / 50, t = i - b * 50, g = glen[b];
  rowmap[i] = b * 50 + ((t < g) ? (g - 1 - t) : t);
}

// ---------------- emb_words output ------------------------------------------
__global__ void gcnk_embw(const int* __restrict__ x, const float* __restrict__ tab,
                          float4* __restrict__ out){
  int idx = blockIdx.x * 256 + threadIdx.x;
  if (idx >= 16000 * 75) return;
  int row = idx / 75, q = idx - row * 75;
  const float4* t = (const float4*)tab;
  out[idx] = t[x[row] * 75 + q];
}

// ---------------- generic zero ----------------------------------------------
__global__ void gcnk_zeroi(unsigned int* __restrict__ p, int n){
  int i = blockIdx.x * 256 + threadIdx.x;
  if (i < n) p[i] = 0u;
}

// ---------------- enc (fp16): enc[m][d] = tab[tok]+pos, pad rows zero -------
__global__ void gcnk_ench(const int* __restrict__ sx, const float* __restrict__ tab,
                          const float* __restrict__ pos, const int* __restrict__ sentlen,
                          _Float16* __restrict__ ench){
  int idx = blockIdx.x * 256 + threadIdx.x;
  if (idx >= MPAD * 300) return;
  int row = idx / 300, d = idx - row * 300;
  float v = 0.f;
  if (row < MROWS){
    int n = row / 40, l = row - n * 40;
    int tok = sx[n * 40 + l];
    int p = (l < sentlen[n]) ? (l + 1) : 0;
    v = tab[tok * 300 + d] + pos[p * 300 + d];
  }
  ench[idx] = (_Float16)v;
}

// ---------------- pack all conv weights into B[320][2112] fp16 + bias[300] --
__global__ void gcnk_bpack(const float* w2, const float* w3, const float* w4,
                           const float* w5, const float* w6, const float* w7,
                           const float* c2, const float* c3, const float* c4,
                           const float* c5, const float* c6, const float* c7,
                           _Float16* __restrict__ Bp, float* __restrict__ bias_p){
  int idx = blockIdx.x * 256 + threadIdx.x;
  if (idx < NPACK * KPACK){
    int n = idx / KPACK, kk = idx - n * KPACK;
    _Float16 v = (_Float16)0.f;
    if (n < 300){
      int H = n / 50 + 2, o = n - (H - 2) * 50;
      if (kk < 300 * H){
        const float* w;
        switch (H){ case 2: w = w2; break; case 3: w = w3; break;
                    case 4: w = w4; break; case 5: w = w5; break;
                    case 6: w = w6; break; default: w = w7; break; }
        v = (_Float16)w[o * 300 * H + kk];
      }
    }
    Bp[idx] = v;
  }
  if (idx < 300){
    int H = idx / 50 + 2, o = idx - (H - 2) * 50;
    const float* cbp;
    switch (H){ case 2: cbp = c2; break; case 3: cbp = c3; break;
                case 4: cbp = c4; break; case 5: cbp = c5; break;
                case 6: cbp = c6; break; default: cbp = c7; break; }
    bias_p[idx] = cbp[o];
  }
}

// ---------------- fused conv GEMM via MFMA f16 ------------------------------
// C[64000][320] = A[m][kk]*B[n][kk]^T, A[m][kk]=enc_flat[m*300+kk] (implicit
// im2col: zero-padded B kills kk>=300H incl. cross-sentence overhang).
// Epilogue: per (sentence, col) relu+window-max -> atomicMax into ngram.
__global__ __launch_bounds__(256)
void gcnk_convmfma(const _Float16* __restrict__ A, const _Float16* __restrict__ Bp,
                   const float* __restrict__ bias_p, unsigned int* __restrict__ ngram_u){
  __shared__ __align__(16) char smem[23040];
  _Float16* As = (_Float16*)smem;            // [128][40]  (pitch 40 halfs)
  _Float16* Bs = (_Float16*)(smem + 10240);  // [160][40]
  float* Cs = (float*)smem;                  // [128][33]  (epilogue passes)
  const int tid = threadIdx.x;
  const int m0 = blockIdx.x * 128, n0 = blockIdx.y * 160;
  const int w = tid >> 6, lane = tid & 63;
  const int wm = (w >> 1) * 64, wn = (w & 1) * 80;
  const int fm = lane & 15, fq = lane >> 4;
  v4f acc[4][5] = {};

  for (int kc = 0; kc < KPACK; kc += 32){
    #pragma unroll
    for (int j = 0; j < 4; j++){            // A stage: 128 rows x 32 halfs
      int u = tid + 256 * j;
      int row = u >> 3, part = u & 7;
      uint2 v = *(const uint2*)(A + (size_t)(m0 + row) * 300 + kc + part * 4);
      *(uint2*)(As + row * 40 + part * 4) = v;
    }
    #pragma unroll
    for (int j = 0; j < 5; j++){            // B stage: 160 rows x 32 halfs
      int u = tid + 256 * j;
      int row = u >> 3, part = u & 7;
      uint2 v = *(const uint2*)(Bp + (size_t)(n0 + row) * KPACK + kc + part * 4);
      *(uint2*)(Bs + row * 40 + part * 4) = v;
    }
    __syncthreads();
    v8h af[4], bf[5];
    #pragma unroll
    for (int mt = 0; mt < 4; mt++)
      af[mt] = *(const v8h*)(As + (wm + mt * 16 + fm) * 40 + fq * 8);
    #pragma unroll
    for (int nt = 0; nt < 5; nt++)
      bf[nt] = *(const v8h*)(Bs + (wn + nt * 16 + fm) * 40 + fq * 8);
    #pragma unroll
    for (int mt = 0; mt < 4; mt++)
      #pragma unroll
      for (int nt = 0; nt < 5; nt++)
        acc[mt][nt] = __builtin_amdgcn_mfma_f32_16x16x32_f16(af[mt], bf[nt], acc[mt][nt], 0, 0, 0);
    __syncthreads();
  }

  // epilogue: 5 passes of 32 cols through LDS
  for (int p = 0; p < 5; p++){
    __syncthreads();
    #pragma unroll
    for (int nt = 0; nt < 5; nt++){
      int cstart = wn + nt * 16;
      if ((cstart >> 5) == p){
        int co = cstart - p * 32 + fm;
        #pragma unroll
        for (int mt = 0; mt < 4; mt++)
          #pragma unroll
          for (int r = 0; r < 4; r++)
            Cs[(wm + mt * 16 + fq * 4 + r) * 33 + co] = acc[mt][nt][r];
      }
    }
    __syncthreads();
    if (tid < 128){
      int cl = tid & 31, si = tid >> 5;
      int colg = n0 + p * 32 + cl;
      if (colg < 300){
        int H = colg / 50 + 2, lh = 41 - H;
        int sent = m0 / 40 + si;
        int rlo = sent * 40; if (rlo < m0) rlo = m0;
        int rhi = sent * 40 + lh; if (rhi > m0 + 128) rhi = m0 + 128;
        if (rlo < rhi){
          float bv = bias_p[colg];
          float vmax = 0.f;
          for (int r = rlo; r < rhi; r++){
            float v = Cs[(r - m0) * 33 + cl] + bv;
            vmax = fmaxf(vmax, v);
          }
          atomicMax(ngram_u + sent * 300 + colg, __float_as_uint(vmax));
        }
      }
    }
  }
}

// ngram += POS_TAB[n % 50]
__global__ void gcnk_addpos(float* __restrict__ ngram, const float* __restrict__ pos){
  int idx = blockIdx.x * 256 + threadIdx.x;
  if (idx >= 1600 * 300) return;
  int row = idx / 300, d = idx - row * 300;
  ngram[idx] += pos[(row % 50) * 300 + d];
}

// ---------------- generic fp32 GEMM: C[M,N] = A[M,K] * W[N,K]^T + b1 + b2 ---
__global__ __launch_bounds__(256)
void gcnk_gemm(const float* __restrict__ A, const float* __restrict__ Wt,
               const float* __restrict__ bias1, const float* __restrict__ bias2,
               float* __restrict__ C, int M, int N, int K){
  __shared__ float As[32][34];
  __shared__ float Ws[32][68];
  const int tid = threadIdx.x;
  const int m0 = blockIdx.x * 32, n0 = blockIdx.y * 64;
  const int i = tid >> 4, j = tid & 15;
  float acc[2][4] = {{0.f,0.f,0.f,0.f},{0.f,0.f,0.f,0.f}};
  for (int kc = 0; kc < K; kc += 32){
    #pragma unroll
    for (int t = 0; t < 4; t++){
      int idx = tid + t * 256;
      int r = idx >> 5, c = idx & 31;
      int gm = m0 + r, gk = kc + c;
      As[c][r] = (gm < M && gk < K) ? A[gm * K + gk] : 0.f;
    }
    #pragma unroll
    for (int t = 0; t < 8; t++){
      int idx = tid + t * 256;
      int r = idx & 63, c = idx >> 6;
      int gn = n0 + r, gk = kc + c;
      Ws[c][r] = (gn < N && gk < K) ? Wt[gn * K + gk] : 0.f;
    }
    __syncthreads();
    #pragma unroll
    for (int kk = 0; kk < 32; kk++){
      const float2 a = *(const float2*)&As[kk][2 * i];
      const float4 w = *(const float4*)&Ws[kk][4 * j];
      acc[0][0] += a.x * w.x; acc[0][1] += a.x * w.y; acc[0][2] += a.x * w.z; acc[0][3] += a.x * w.w;
      acc[1][0] += a.y * w.x; acc[1][1] += a.y * w.y; acc[1][2] += a.y * w.z; acc[1][3] += a.y * w.w;
    }
    __syncthreads();
  }
  #pragma unroll
  for (int r = 0; r < 2; r++){
    int gm = m0 + 2 * i + r;
    if (gm >= M) continue;
    #pragma unroll
    for (int cc = 0; cc < 4; cc++){
      int gn = n0 + 4 * j + cc;
      if (gn >= N) continue;
      float v = acc[r][cc];
      if (bias1) v += bias1[gn];
      if (bias2) v += bias2[gn];
      C[gm * N + gn] = v;
    }
  }
}

// ---------------- row permute / concat --------------------------------------
__global__ void gcnk_permute150(float* __restrict__ dst, const float* __restrict__ src,
                                const int* __restrict__ map){
  int idx = blockIdx.x * 256 + threadIdx.x;
  if (idx >= 1600 * 150) return;
  int row = idx / 150, d = idx - row * 150;
  dst[idx] = src[map[row] * 150 + d];
}

__global__ void gcnk_concat(float* __restrict__ dst, const float* __restrict__ A,
                            const float* __restrict__ Bs, const int* __restrict__ mapA,
                            const int* __restrict__ mapB, const int* __restrict__ glen,
                            int usemask){
  int idx = blockIdx.x * 256 + threadIdx.x;
  if (idx >= 1600 * 300) return;
  int row = idx / 300, d = idx - row * 300;
  int b = row / 50, t = row - b * 50;
  float v;
  if (d < 150){ int r = mapA ? mapA[row] : row; v = A[r * 150 + d]; }
  else        { int r = mapB ? mapB[row] : row; v = Bs[r * 150 + d - 150]; }
  if (usemask && t >= glen[b]) v = 0.f;
  dst[idx] = v;
}

// ---------------- lstm whh -> fp16, rows padded 150 -> 152 ------------------
__global__ void gcnk_whhpack(const float* __restrict__ whh, _Float16* __restrict__ wpad){
  int idx = blockIdx.x * 256 + threadIdx.x;
  if (idx >= 1200 * 152) return;
  int row = idx / 152, col = idx - row * 152;
  wpad[idx] = (col < 150) ? (_Float16)whh[row * 150 + col] : (_Float16)0.f;
}

// ---------------- LSTM recurrence: weights in VGPRs, h fp16 in LDS ----------
__global__ __launch_bounds__(640)
void gcnk_lstm(const float* __restrict__ xf, const float* __restrict__ xr,
               const _Float16* __restrict__ wpad, float* __restrict__ fo,
               float* __restrict__ ro){
  int b = blockIdx.x >> 1, dir = blockIdx.x & 1;
  const float* xih = dir ? xr : xf;
  float* out = dir ? ro : fo;
  __shared__ __align__(16) _Float16 hh[160];
  __shared__ float gates[600];
  const int tid = threadIdx.x;

  h2 w[76];
  if (tid < 600){
    const h2* wrow = (const h2*)(wpad + ((size_t)dir * 600 + tid) * 152);
    #pragma unroll
    for (int j = 0; j < 76; j++) w[j] = wrow[j];
  }
  for (int u = tid; u < 160; u += 640) hh[u] = (_Float16)0.f;
  float creg = 0.f;
  __syncthreads();

  for (int t = 0; t < 50; t++){
    if (tid < 600){
      float acc = xih[(b * 50 + t) * 600 + tid];
      #pragma unroll
      for (int j = 0; j < 19; j++){
        union { float4 f; h2 h[4]; } u;
        u.f = *(const float4*)(hh + j * 8);
        acc = fdot2_(w[4 * j + 0], u.h[0], acc);
        acc = fdot2_(w[4 * j + 1], u.h[1], acc);
        acc = fdot2_(w[4 * j + 2], u.h[2], acc);
        acc = fdot2_(w[4 * j + 3], u.h[3], acc);
      }
      gates[tid] = acc;
    }
    __syncthreads();
    if (tid < 150){
      float ig = sigm(gates[tid]);
      float fg = sigm(gates[150 + tid]);
      float gg = tanhf(gates[300 + tid]);
      float og = sigm(gates[450 + tid]);
      creg = fg * creg + ig * gg;
      float hn = og * tanhf(creg);
      hh[tid] = (_Float16)hn;
      out[(b * 50 + t) * 150 + tid] = hn;
    }
    __syncthreads();
  }
}

// ---------------- node feature assembly [17600 x 300] -----------------------
__global__ void gcnk_nodes_in(const int* __restrict__ x, const float* __restrict__ tab,
                              const float* __restrict__ cnnf, const float* __restrict__ lstmf,
                              float* __restrict__ out){
  int idx = blockIdx.x * 256 + threadIdx.x;
  if (idx >= NNODES * 300) return;
  int nrow = idx / 300, d = idx - nrow * 300;
  int b = nrow / 550, j = nrow - b * 550;
  float v;
  if (j < 500) v = tab[x[b * 500 + j] * 300 + d];
  else {
    int r = b * 50 + (j - 500);
    v = (d < 150) ? cnnf[r * 150 + d] : lstmf[r * 150 + d - 150];
  }
  out[idx] = v;
}

// ---------------- GCN: CSR build (counting sort by dst) ---------------------
__global__ void gcnk_hist(const int* __restrict__ ei, int* __restrict__ ecnt){
  int e = blockIdx.x * 256 + threadIdx.x;
  if (e < EDGES) atomicAdd(&ecnt[ei[EDGES + e]], 1);
}

__global__ __launch_bounds__(1024)
void gcnk_scan(const int* __restrict__ ecnt, int* __restrict__ eoff,
               int* __restrict__ ecur){
  __shared__ int buf[1024];
  int tid = threadIdx.x;
  int running = 0;
  for (int c = 0; c < 18; c++){
    int i = c * 1024 + tid;
    int v = (i < NNODES) ? ecnt[i] : 0;
    buf[tid] = v;
    __syncthreads();
    for (int s = 1; s < 1024; s <<= 1){
      int t2 = (tid >= s) ? buf[tid - s] : 0;
      __syncthreads();
      buf[tid] += t2;
      __syncthreads();
    }
    int excl = running + buf[tid] - v;
    int tot = buf[1023];
    if (i < NNODES){ eoff[i] = excl; ecur[i] = excl; }
    running += tot;
    __syncthreads();
  }
}

__global__ void gcnk_scatter(const int* __restrict__ ei, int* __restrict__ ecur,
                             int* __restrict__ esrc){
  int e = blockIdx.x * 256 + threadIdx.x;
  if (e < EDGES){
    int d = ei[EDGES + e];
    int p = atomicAdd(&ecur[d], 1);
    esrc[p] = ei[e];
  }
}

__global__ void gcnk_dis2(const int* __restrict__ ecnt, float* __restrict__ dis){
  int i = blockIdx.x * 256 + threadIdx.x;
  if (i < NNODES) dis[i] = rsqrtf((float)(ecnt[i] + 1));
}

// ---------------- GCN aggregation: CSR gather, no atomics -------------------
__global__ __launch_bounds__(128)
void gcnk_aggcsr(const int* __restrict__ eoff, const int* __restrict__ ecnt,
                 const int* __restrict__ esrc, const float* __restrict__ dis,
                 const float* __restrict__ xw, float* __restrict__ agg){
  int d = blockIdx.x, t = threadIdx.x;
  float dd = dis[d];
  const float* xd = xw + (size_t)d * 150;
  float a0 = xd[t] * dd;
  float a1 = (t < 22) ? xd[128 + t] * dd : 0.f;
  int beg = eoff[d], end = beg + ecnt[d];
  for (int j = beg; j < end; j++){
    int s = esrc[j];
    float ds = dis[s];
    const float* xs = xw + (size_t)s * 150;
    a0 += xs[t] * ds;
    if (t < 22) a1 += xs[128 + t] * ds;
  }
  agg[(size_t)d * 150 + t] = a0 * dd;
  if (t < 22) agg[(size_t)d * 150 + 128 + t] = a1 * dd;
}

__global__ void gcnk_elu(float* __restrict__ h, const float* __restrict__ agg,
                         const float* __restrict__ bias){
  int idx = blockIdx.x * 256 + threadIdx.x;
  if (idx >= NNODES * 150) return;
  int c = idx % 150;
  float v = agg[idx] + bias[c];
  h[idx] = (v > 0.f) ? v : expm1f(v);
}

__global__ void gcnk_out0(float* __restrict__ out, const float* __restrict__ agg,
                          const float* __restrict__ bias){
  int idx = blockIdx.x * 256 + threadIdx.x;
  if (idx >= NNODES * 150) return;
  int c = idx % 150;
  out[idx] = agg[idx] + bias[c];
}

// ============================================================================
extern "C" void kernel_launch(void* const* d_in, const int* in_sizes, int n_in,
                              void* d_out, int out_size, void* d_ws, size_t ws_size,
                              hipStream_t stream){
  (void)in_sizes; (void)n_in; (void)out_size; (void)ws_size;

  char* wsb = (char*)d_ws;
  size_t off = 0;
  auto alloc = [&](size_t bytes) -> void* {
    void* p = wsb + off;
    off = (off + bytes + 255) & ~(size_t)255;
    return p;
  };
  float* pos_tab  = (float*)alloc(513 * 300 * 4);
  int*   sentlen  = (int*)alloc(1600 * 4);
  int*   glen     = (int*)alloc(32 * 4);
  int*   rowmap   = (int*)alloc(1600 * 4);
  float* ngram    = (float*)alloc(1600 * 300 * 4);
  float* cnn_feat = (float*)alloc(1600 * 150 * 4);
  float* cnn_rev  = (float*)alloc(1600 * 150 * 4);
  float* xih_f    = (float*)alloc(1600 * 600 * 4);
  float* xih_r    = (float*)alloc(1600 * 600 * 4);
  float* f0       = (float*)alloc(1600 * 150 * 4);
  float* r0       = (float*)alloc(1600 * 150 * 4);
  float* f1       = (float*)alloc(1600 * 150 * 4);
  float* r1       = (float*)alloc(1600 * 150 * 4);
  float* h1       = (float*)alloc(1600 * 300 * 4);
  float* h1rev    = (float*)alloc(1600 * 300 * 4);
  float* hm       = (float*)alloc(1600 * 300 * 4);
  float* lstm_ft  = (float*)alloc(1600 * 150 * 4);
  float* nodes_in = (float*)alloc((size_t)NNODES * 300 * 4);
  float* nodes    = (float*)alloc((size_t)NNODES * 150 * 4);
  float* dis      = (float*)alloc(NNODES * 4);
  float* xw       = (float*)alloc((size_t)NNODES * 150 * 4);
  float* agg      = (float*)alloc((size_t)NNODES * 150 * 4);
  _Float16* ench  = (_Float16*)alloc((size_t)MPAD * 300 * 2);
  _Float16* Bp    = (_Float16*)alloc((size_t)NPACK * KPACK * 2);
  float* bias_p   = (float*)alloc(320 * 4);
  _Float16* wpad0 = (_Float16*)alloc(1200 * 152 * 2);
  _Float16* wpad1 = (_Float16*)alloc(1200 * 152 * 2);
  int*   ecnt     = (int*)alloc(NNODES * 4);
  int*   eoff     = (int*)alloc(NNODES * 4);
  int*   ecur     = (int*)alloc(NNODES * 4);
  int*   esrc     = (int*)alloc(EDGES * 4);

  const int*   x   = (const int*)d_in[0];
  const int*   sx  = (const int*)d_in[1];
  const int*   ei  = (const int*)d_in[2];
  const float* tab = (const float*)d_in[3];
  const float *cw[6], *cb[6];
  for (int h = 0; h < 6; h++){ cw[h] = (const float*)d_in[4 + 2 * h]; cb[h] = (const float*)d_in[5 + 2 * h]; }
  const float* cnnw = (const float*)d_in[16]; const float* cnnb = (const float*)d_in[17];
  const float* wih0 = (const float*)d_in[18]; const float* whh0 = (const float*)d_in[19];
  const float* bih0 = (const float*)d_in[20]; const float* bhh0 = (const float*)d_in[21];
  const float* wih1 = (const float*)d_in[22]; const float* whh1 = (const float*)d_in[23];
  const float* bih1 = (const float*)d_in[24]; const float* bhh1 = (const float*)d_in[25];
  const float* lpw  = (const float*)d_in[26]; const float* lpb  = (const float*)d_in[27];
  const float* g0w  = (const float*)d_in[28]; const float* g0b  = (const float*)d_in[29];
  const float* g1w  = (const float*)d_in[30]; const float* g1b  = (const float*)d_in[31];
  const float* g2w  = (const float*)d_in[32]; const float* g2b  = (const float*)d_in[33];

  float* out0 = (float*)d_out;
  float4* out1 = (float4*)((float*)d_out + OUT0SZ);

  auto gemm = [&](const float* A, const float* W, const float* b1, const float* b2,
                  float* C, int M, int N, int K){
    dim3 g((M + 31) / 32, (N + 63) / 64);
    gcnk_gemm<<<g, 256, 0, stream>>>(A, W, b1, b2, C, M, N, K);
  };

  // ---- pipeline ----
  gcnk_postab<<<602, 256, 0, stream>>>(pos_tab);
  gcnk_prep<<<7, 256, 0, stream>>>(sx, sentlen, glen);
  gcnk_rowmap<<<7, 256, 0, stream>>>(glen, rowmap);
  gcnk_embw<<<4688, 256, 0, stream>>>(x, tab, out1);

  // conv: fused implicit-im2col MFMA GEMM over all 6 heads
  gcnk_zeroi<<<1875, 256, 0, stream>>>((unsigned int*)ngram, 1600 * 300);
  gcnk_ench<<<(MPAD * 300 + 255) / 256, 256, 0, stream>>>(sx, tab, pos_tab, sentlen, ench);
  gcnk_bpack<<<(NPACK * KPACK + 255) / 256, 256, 0, stream>>>(
      cw[0], cw[1], cw[2], cw[3], cw[4], cw[5],
      cb[0], cb[1], cb[2], cb[3], cb[4], cb[5], Bp, bias_p);
  gcnk_whhpack<<<713, 256, 0, stream>>>(whh0, wpad0);
  gcnk_whhpack<<<713, 256, 0, stream>>>(whh1, wpad1);
  {
    dim3 g(500, 2);
    gcnk_convmfma<<<g, 256, 0, stream>>>(ench, Bp, bias_p, (unsigned int*)ngram);
  }
  gcnk_addpos<<<1875, 256, 0, stream>>>(ngram, pos_tab);
  gemm(ngram, cnnw, cnnb, nullptr, cnn_feat, 1600, 150, 300);

  // BiLSTM layer 0
  gcnk_permute150<<<938, 256, 0, stream>>>(cnn_rev, cnn_feat, rowmap);
  gemm(cnn_feat, wih0,             bih0,       bhh0,       xih_f, 1600, 600, 150);
  gemm(cnn_rev,  wih0 + 600 * 150, bih0 + 600, bhh0 + 600, xih_r, 1600, 600, 150);
  gcnk_lstm<<<64, 640, 0, stream>>>(xih_f, xih_r, wpad0, f0, r0);

  // BiLSTM layer 1
  gcnk_concat<<<1875, 256, 0, stream>>>(h1,    f0, r0, nullptr, rowmap, glen, 0);
  gcnk_concat<<<1875, 256, 0, stream>>>(h1rev, f0, r0, rowmap, nullptr, glen, 0);
  gemm(h1,    wih1,             bih1,       bhh1,       xih_f, 1600, 600, 300);
  gemm(h1rev, wih1 + 600 * 300, bih1 + 600, bhh1 + 600, xih_r, 1600, 600, 300);
  gcnk_lstm<<<64, 640, 0, stream>>>(xih_f, xih_r, wpad1, f1, r1);

  // masked projection
  gcnk_concat<<<1875, 256, 0, stream>>>(hm, f1, r1, nullptr, rowmap, glen, 1);
  gemm(hm, lpw, lpb, nullptr, lstm_ft, 1600, 150, 300);

  // node features + gc0
  gcnk_nodes_in<<<20625, 256, 0, stream>>>(x, tab, cnn_feat, lstm_ft, nodes_in);
  gemm(nodes_in, g0w, g0b, nullptr, nodes, NNODES, 150, 300);

  // CSR build (once, reused by both GCN layers)
  gcnk_zeroi<<<69, 256, 0, stream>>>((unsigned int*)ecnt, NNODES);
  gcnk_hist<<<2200, 256, 0, stream>>>(ei, ecnt);
  gcnk_scan<<<1, 1024, 0, stream>>>(ecnt, eoff, ecur);
  gcnk_scatter<<<2200, 256, 0, stream>>>(ei, ecur, esrc);
  gcnk_dis2<<<69, 256, 0, stream>>>(ecnt, dis);

  // gc1 + elu
  gemm(nodes, g1w, nullptr, nullptr, xw, NNODES, 150, 150);
  gcnk_aggcsr<<<NNODES, 128, 0, stream>>>(eoff, ecnt, esrc, dis, xw, agg);
  gcnk_elu<<<10313, 256, 0, stream>>>(nodes, agg, g1b);

  // gc2 -> output 0
  gemm(nodes, g2w, nullptr, nullptr, xw, NNODES, 150, 150);
  gcnk_aggcsr<<<NNODES, 128, 0, stream>>>(eoff, ecnt, esrc, dis, xw, agg);
  gcnk_out0<<<10313, 256, 0, stream>>>(out0, agg, g2b);
}

// Round 6
// 903.503 us; speedup vs baseline: 4.6519x; 1.4461x over previous
//
#include <hip/hip_runtime.h>
#include <stdint.h>
#include <math.h>

// Problem constants (match reference)
#define EDGES 563200
#define NNODES 17600    // B*(NW+NS)
#define OUT0SZ 2640000  // 17600*150
#define MROWS 64000     // 1600 sentences * 40 positions
#define MPAD  64016     // + zero pad rows for window overhang
#define KSTRIDE 2112    // B pack row stride (halfs)

typedef _Float16 h2 __attribute__((ext_vector_type(2)));
typedef _Float16 h4 __attribute__((ext_vector_type(4)));
typedef _Float16 v8h __attribute__((ext_vector_type(8)));
typedef float v4f __attribute__((ext_vector_type(4)));

__device__ __forceinline__ float sigm(float x){ return 1.f / (1.f + expf(-x)); }

__device__ __forceinline__ float fdot2_(h2 a, h2 b, float c){
#if __has_builtin(__builtin_amdgcn_fdot2)
  return __builtin_amdgcn_fdot2(a, b, c, false);
#else
  return c + (float)a.x * (float)b.x + (float)a.y * (float)b.y;
#endif
}

// ---------------- POS table (numpy float64 sinusoid, row 0 zeroed) ----------
__global__ void gcnk_postab(float* __restrict__ pos){
  int idx = blockIdx.x * 256 + threadIdx.x;
  if (idx >= 513 * 300) return;
  int p = idx / 300, i = idx - p * 300;
  float v = 0.f;
  if (p != 0){
    double expo = (double)(2 * (i / 2)) / 300.0;
    double ang = (double)p / pow(10000.0, expo);
    v = (float)((i & 1) ? cos(ang) : sin(ang));
  }
  pos[idx] = v;
}

// ---------------- sentlen + glen --------------------------------------------
__global__ void gcnk_prep(const int* __restrict__ sx, int* __restrict__ sentlen,
                          int* __restrict__ glen){
  int tid = blockIdx.x * 256 + threadIdx.x;
  if (tid < 1600){
    int c = 0;
    for (int j = 0; j < 40; j++) c += (sx[tid * 40 + j] != 0);
    sentlen[tid] = c;
  } else if (tid < 1632){
    int b = tid - 1600, c = 0;
    for (int s = 0; s < 50; s++) c += (sx[b * 2000 + s * 40] != 0);
    glen[b] = c;
  }
}

__global__ void gcnk_rowmap(const int* __restrict__ glen, int* __restrict__ rowmap){
  int i = blockIdx.x * 256 + threadIdx.x;
  if (i >= 1600) return;
  int b = i / 50, t = i - b * 50, g = glen[b];
  rowmap[i] = b * 50 + ((t < g) ? (g - 1 - t) : t);
}

// ---------------- emb_words output ------------------------------------------
__global__ void gcnk_embw(const int* __restrict__ x, const float* __restrict__ tab,
                          float4* __restrict__ out){
  int idx = blockIdx.x * 256 + threadIdx.x;
  if (idx >= 16000 * 75) return;
  int row = idx / 75, q = idx - row * 75;
  const float4* t = (const float4*)tab;
  out[idx] = t[x[row] * 75 + q];
}

// ---------------- generic zero ----------------------------------------------
__global__ void gcnk_zeroi(unsigned int* __restrict__ p, int n){
  int i = blockIdx.x * 256 + threadIdx.x;
  if (i < n) p[i] = 0u;
}

// ---------------- enc (fp16): enc[m][d] = tab[tok]+pos, pad rows zero -------
__global__ void gcnk_ench(const int* __restrict__ sx, const float* __restrict__ tab,
                          const float* __restrict__ pos, const int* __restrict__ sentlen,
                          _Float16* __restrict__ ench){
  int idx = blockIdx.x * 256 + threadIdx.x;
  if (idx >= MPAD * 75) return;
  int row = idx / 75, q = idx - row * 75;
  int d = q * 4;
  h4 o; o[0] = (_Float16)0.f; o[1] = (_Float16)0.f; o[2] = (_Float16)0.f; o[3] = (_Float16)0.f;
  if (row < MROWS){
    int n = row / 40, l = row - n * 40;
    int tok = sx[n * 40 + l];
    int p = (l < sentlen[n]) ? (l + 1) : 0;
    float4 a = *(const float4*)(tab + (size_t)tok * 300 + d);
    float4 b = *(const float4*)(pos + (size_t)p * 300 + d);
    o[0] = (_Float16)(a.x + b.x); o[1] = (_Float16)(a.y + b.y);
    o[2] = (_Float16)(a.z + b.z); o[3] = (_Float16)(a.w + b.w);
  }
  *(h4*)(ench + (size_t)row * 300 + d) = o;
}

// ---------------- pack conv weights: Bp[2][160][2112] fp16 + bias[320] ------
// group g holds heads 3g+2..3g+4 (cols 0..149), cols 150..159 zero.
__global__ void gcnk_bpack(const float* w2, const float* w3, const float* w4,
                           const float* w5, const float* w6, const float* w7,
                           const float* c2, const float* c3, const float* c4,
                           const float* c5, const float* c6, const float* c7,
                           _Float16* __restrict__ Bp, float* __restrict__ bias_p){
  int idx = blockIdx.x * 256 + threadIdx.x;
  if (idx < 2 * 160 * KSTRIDE){
    int n = idx / KSTRIDE, kk = idx - n * KSTRIDE;
    int g = n / 160, c = n - g * 160;
    _Float16 v = (_Float16)0.f;
    if (c < 150){
      int H = 3 * g + 2 + c / 50, o = c % 50;
      if (kk < 300 * H){
        const float* w;
        switch (H){ case 2: w = w2; break; case 3: w = w3; break;
                    case 4: w = w4; break; case 5: w = w5; break;
                    case 6: w = w6; break; default: w = w7; break; }
        v = (_Float16)w[o * 300 * H + kk];
      }
    }
    Bp[idx] = v;
  }
  if (idx < 320){
    int g = idx / 160, c = idx - g * 160;
    float bv = 0.f;
    if (c < 150){
      int H = 3 * g + 2 + c / 50, o = c % 50;
      const float* cbp;
      switch (H){ case 2: cbp = c2; break; case 3: cbp = c3; break;
                  case 4: cbp = c4; break; case 5: cbp = c5; break;
                  case 6: cbp = c6; break; default: cbp = c7; break; }
      bv = cbp[o];
    }
    bias_p[idx] = bv;
  }
}

// ---------------- fused conv GEMM via MFMA f16, K-split by head group -------
__global__ __launch_bounds__(256)
void gcnk_convmfma(const _Float16* __restrict__ A, const _Float16* __restrict__ Bp,
                   const float* __restrict__ bias_p, unsigned int* __restrict__ ngram_u){
  __shared__ __align__(16) char smem[23040];
  _Float16* As = (_Float16*)smem;            // [128][40]
  _Float16* Bs = (_Float16*)(smem + 10240);  // [160][40]
  float* Cs = (float*)smem;                  // [128][33] (epilogue)
  const int tid = threadIdx.x;
  const int m0 = blockIdx.x * 128;
  const int grp = blockIdx.y;
  const _Float16* Bg = Bp + (size_t)grp * 160 * KSTRIDE;
  const int kmax = grp ? 2112 : 1216;        // heads 2-4 need K<=1200
  const int w = tid >> 6, lane = tid & 63;
  const int wm = (w >> 1) * 64, wn = (w & 1) * 80;
  const int fm = lane & 15, fq = lane >> 4;
  v4f acc[4][5] = {};

  for (int kc = 0; kc < kmax; kc += 32){
    #pragma unroll
    for (int j = 0; j < 4; j++){            // A stage: 128 rows x 32 halfs
      int u = tid + 256 * j;
      int row = u >> 3, part = u & 7;
      uint2 v = *(const uint2*)(A + (size_t)(m0 + row) * 300 + kc + part * 4);
      *(uint2*)(As + row * 40 + part * 4) = v;
    }
    #pragma unroll
    for (int j = 0; j < 5; j++){            // B stage: 160 rows x 32 halfs
      int u = tid + 256 * j;
      int row = u >> 3, part = u & 7;
      uint2 v = *(const uint2*)(Bg + (size_t)row * KSTRIDE + kc + part * 4);
      *(uint2*)(Bs + row * 40 + part * 4) = v;
    }
    __syncthreads();
    v8h af[4], bf[5];
    #pragma unroll
    for (int mt = 0; mt < 4; mt++)
      af[mt] = *(const v8h*)(As + (wm + mt * 16 + fm) * 40 + fq * 8);
    #pragma unroll
    for (int nt = 0; nt < 5; nt++)
      bf[nt] = *(const v8h*)(Bs + (wn + nt * 16 + fm) * 40 + fq * 8);
    #pragma unroll
    for (int mt = 0; mt < 4; mt++)
      #pragma unroll
      for (int nt = 0; nt < 5; nt++)
        acc[mt][nt] = __builtin_amdgcn_mfma_f32_16x16x32_f16(af[mt], bf[nt], acc[mt][nt], 0, 0, 0);
    __syncthreads();
  }

  // epilogue: 5 passes of 32 cols through LDS; relu+window-max -> atomicMax
  for (int p = 0; p < 5; p++){
    __syncthreads();
    #pragma unroll
    for (int nt = 0; nt < 5; nt++){
      int cstart = wn + nt * 16;
      if ((cstart >> 5) == p){
        int co = cstart - p * 32 + fm;
        #pragma unroll
        for (int mt = 0; mt < 4; mt++)
          #pragma unroll
          for (int r = 0; r < 4; r++)
            Cs[(wm + mt * 16 + fq * 4 + r) * 33 + co] = acc[mt][nt][r];
      }
    }
    __syncthreads();
    if (tid < 128){
      int cl = tid & 31, si = tid >> 5;
      int col = p * 32 + cl;               // group-local col
      if (col < 150){
        int H = 3 * grp + 2 + col / 50, lh = 41 - H;
        int sent = m0 / 40 + si;
        int rlo = sent * 40; if (rlo < m0) rlo = m0;
        int rhi = sent * 40 + lh; if (rhi > m0 + 128) rhi = m0 + 128;
        if (rlo < rhi){
          float bv = bias_p[grp * 160 + col];
          float vmax = 0.f;
          for (int r = rlo; r < rhi; r++){
            float v = Cs[(r - m0) * 33 + cl] + bv;
            vmax = fmaxf(vmax, v);
          }
          atomicMax(ngram_u + sent * 300 + grp * 150 + col, __float_as_uint(vmax));
        }
      }
    }
  }
}

// ngram += POS_TAB[n % 50]
__global__ void gcnk_addpos(float* __restrict__ ngram, const float* __restrict__ pos){
  int idx = blockIdx.x * 256 + threadIdx.x;
  if (idx >= 1600 * 300) return;
  int row = idx / 300, d = idx - row * 300;
  ngram[idx] += pos[(row % 50) * 300 + d];
}

// ---------------- MFMA GEMM: C[M,N] = A[M,K](fp32->fp16) @ Wt[N,K]^T + b ----
template<int BM, int BN, int WMT, int WNT>
__global__ __launch_bounds__(256)
void gcnk_mgemm(const float* __restrict__ A, const float* __restrict__ Wt,
                const float* __restrict__ b1, const float* __restrict__ b2,
                float* __restrict__ C, int M, int N, int K){
  __shared__ __align__(16) _Float16 As[BM * 40];
  __shared__ __align__(16) _Float16 Bs[BN * 40];
  const int tid = threadIdx.x;
  const int m0 = blockIdx.x * BM, n0 = blockIdx.y * BN;
  const int w = tid >> 6, lane = tid & 63;
  const int wm = (w >> 1) * (WMT * 16), wn = (w & 1) * (WNT * 16);
  const int fm = lane & 15, fq = lane >> 4;
  v4f acc[WMT][WNT] = {};
  const int nch = (K + 31) >> 5;
  for (int ch = 0; ch < nch; ch++){
    int kc = ch * 32;
    #pragma unroll
    for (int j = 0; j < BM / 64; j++){      // A stage: BM rows x 32 halfs
      int u = tid + 256 * j;
      int row = u >> 2, cb = (u & 3) * 8;
      int gm = m0 + row, gk = kc + cb;
      v8h vv;
      if (gm < M && gk + 8 <= K){
        const float* p = A + (size_t)gm * K + gk;
        #pragma unroll
        for (int e = 0; e < 8; e++) vv[e] = (_Float16)p[e];
      } else {
        #pragma unroll
        for (int e = 0; e < 8; e++)
          vv[e] = (gm < M && gk + e < K) ? (_Float16)A[(size_t)gm * K + gk + e] : (_Float16)0.f;
      }
      *(v8h*)(As + row * 40 + cb) = vv;
    }
    {                                        // B stage: BN(=64) rows x 32 halfs
      int row = tid >> 2, cb = (tid & 3) * 8;
      int gn = n0 + row, gk = kc + cb;
      v8h vv;
      if (gn < N && gk + 8 <= K){
        const float* p = Wt + (size_t)gn * K + gk;
        #pragma unroll
        for (int e = 0; e < 8; e++) vv[e] = (_Float16)p[e];
      } else {
        #pragma unroll
        for (int e = 0; e < 8; e++)
          vv[e] = (gn < N && gk + e < K) ? (_Float16)Wt[(size_t)gn * K + gk + e] : (_Float16)0.f;
      }
      *(v8h*)(Bs + row * 40 + cb) = vv;
    }
    __syncthreads();
    v8h af[WMT], bf[WNT];
    #pragma unroll
    for (int mt = 0; mt < WMT; mt++)
      af[mt] = *(const v8h*)(As + (wm + mt * 16 + fm) * 40 + fq * 8);
    #pragma unroll
    for (int nt = 0; nt < WNT; nt++)
      bf[nt] = *(const v8h*)(Bs + (wn + nt * 16 + fm) * 40 + fq * 8);
    #pragma unroll
    for (int mt = 0; mt < WMT; mt++)
      #pragma unroll
      for (int nt = 0; nt < WNT; nt++)
        acc[mt][nt] = __builtin_amdgcn_mfma_f32_16x16x32_f16(af[mt], bf[nt], acc[mt][nt], 0, 0, 0);
    __syncthreads();
  }
  #pragma unroll
  for (int nt = 0; nt < WNT; nt++){
    int gn = n0 + wn + nt * 16 + fm;
    if (gn >= N) continue;
    float badd = (b1 ? b1[gn] : 0.f) + (b2 ? b2[gn] : 0.f);
    #pragma unroll
    for (int mt = 0; mt < WMT; mt++)
      #pragma unroll
      for (int r = 0; r < 4; r++){
        int gm = m0 + wm + mt * 16 + fq * 4 + r;
        if (gm < M) C[(size_t)gm * N + gn] = acc[mt][nt][r] + badd;
      }
  }
}

// ---------------- row permute / concat --------------------------------------
__global__ void gcnk_permute150(float* __restrict__ dst, const float* __restrict__ src,
                                const int* __restrict__ map){
  int idx = blockIdx.x * 256 + threadIdx.x;
  if (idx >= 1600 * 150) return;
  int row = idx / 150, d = idx - row * 150;
  dst[idx] = src[map[row] * 150 + d];
}

__global__ void gcnk_concat(float* __restrict__ dst, const float* __restrict__ A,
                            const float* __restrict__ Bs, const int* __restrict__ mapA,
                            const int* __restrict__ mapB, const int* __restrict__ glen,
                            int usemask){
  int idx = blockIdx.x * 256 + threadIdx.x;
  if (idx >= 1600 * 300) return;
  int row = idx / 300, d = idx - row * 300;
  int b = row / 50, t = row - b * 50;
  float v;
  if (d < 150){ int r = mapA ? mapA[row] : row; v = A[r * 150 + d]; }
  else        { int r = mapB ? mapB[row] : row; v = Bs[r * 150 + d - 150]; }
  if (usemask && t >= glen[b]) v = 0.f;
  dst[idx] = v;
}

// ---------------- lstm whh -> fp16, rows padded 150 -> 152 ------------------
__global__ void gcnk_whhpack(const float* __restrict__ whh, _Float16* __restrict__ wpad){
  int idx = blockIdx.x * 256 + threadIdx.x;
  if (idx >= 1200 * 152) return;
  int row = idx / 152, col = idx - row * 152;
  wpad[idx] = (col < 150) ? (_Float16)whh[row * 150 + col] : (_Float16)0.f;
}

// ---------------- LSTM recurrence: weights in VGPRs, h fp16 in LDS ----------
__global__ __launch_bounds__(640)
void gcnk_lstm(const float* __restrict__ xf, const float* __restrict__ xr,
               const _Float16* __restrict__ wpad, float* __restrict__ fo,
               float* __restrict__ ro){
  int b = blockIdx.x >> 1, dir = blockIdx.x & 1;
  const float* xih = dir ? xr : xf;
  float* out = dir ? ro : fo;
  __shared__ __align__(16) _Float16 hh[160];
  __shared__ float gates[600];
  const int tid = threadIdx.x;

  h2 w[76];
  if (tid < 600){
    const h2* wrow = (const h2*)(wpad + ((size_t)dir * 600 + tid) * 152);
    #pragma unroll
    for (int j = 0; j < 76; j++) w[j] = wrow[j];
  }
  for (int u = tid; u < 160; u += 640) hh[u] = (_Float16)0.f;
  float creg = 0.f;
  __syncthreads();

  for (int t = 0; t < 50; t++){
    if (tid < 600){
      float acc = xih[(b * 50 + t) * 600 + tid];
      #pragma unroll
      for (int j = 0; j < 19; j++){
        union { float4 f; h2 h[4]; } u;
        u.f = *(const float4*)(hh + j * 8);
        acc = fdot2_(w[4 * j + 0], u.h[0], acc);
        acc = fdot2_(w[4 * j + 1], u.h[1], acc);
        acc = fdot2_(w[4 * j + 2], u.h[2], acc);
        acc = fdot2_(w[4 * j + 3], u.h[3], acc);
      }
      gates[tid] = acc;
    }
    __syncthreads();
    if (tid < 150){
      float ig = sigm(gates[tid]);
      float fg = sigm(gates[150 + tid]);
      float gg = tanhf(gates[300 + tid]);
      float og = sigm(gates[450 + tid]);
      creg = fg * creg + ig * gg;
      float hn = og * tanhf(creg);
      hh[tid] = (_Float16)hn;
      out[(b * 50 + t) * 150 + tid] = hn;
    }
    __syncthreads();
  }
}

// ---------------- node feature assembly [17600 x 300] -----------------------
__global__ void gcnk_nodes_in(const int* __restrict__ x, const float* __restrict__ tab,
                              const float* __restrict__ cnnf, const float* __restrict__ lstmf,
                              float* __restrict__ out){
  int idx = blockIdx.x * 256 + threadIdx.x;
  if (idx >= NNODES * 300) return;
  int nrow = idx / 300, d = idx - nrow * 300;
  int b = nrow / 550, j = nrow - b * 550;
  float v;
  if (j < 500) v = tab[x[b * 500 + j] * 300 + d];
  else {
    int r = b * 50 + (j - 500);
    v = (d < 150) ? cnnf[r * 150 + d] : lstmf[r * 150 + d - 150];
  }
  out[idx] = v;
}

// ---------------- GCN: CSR build (counting sort by dst) ---------------------
__global__ void gcnk_hist(const int* __restrict__ ei, int* __restrict__ ecnt){
  int e = blockIdx.x * 256 + threadIdx.x;
  if (e < EDGES) atomicAdd(&ecnt[ei[EDGES + e]], 1);
}

__global__ __launch_bounds__(1024)
void gcnk_scan(const int* __restrict__ ecnt, int* __restrict__ eoff,
               int* __restrict__ ecur){
  __shared__ int buf[1024];
  int tid = threadIdx.x;
  int running = 0;
  for (int c = 0; c < 18; c++){
    int i = c * 1024 + tid;
    int v = (i < NNODES) ? ecnt[i] : 0;
    buf[tid] = v;
    __syncthreads();
    for (int s = 1; s < 1024; s <<= 1){
      int t2 = (tid >= s) ? buf[tid - s] : 0;
      __syncthreads();
      buf[tid] += t2;
      __syncthreads();
    }
    int excl = running + buf[tid] - v;
    int tot = buf[1023];
    if (i < NNODES){ eoff[i] = excl; ecur[i] = excl; }
    running += tot;
    __syncthreads();
  }
}

__global__ void gcnk_scatter(const int* __restrict__ ei, int* __restrict__ ecur,
                             int* __restrict__ esrc){
  int e = blockIdx.x * 256 + threadIdx.x;
  if (e < EDGES){
    int d = ei[EDGES + e];
    int p = atomicAdd(&ecur[d], 1);
    esrc[p] = ei[e];
  }
}

__global__ void gcnk_dis2(const int* __restrict__ ecnt, float* __restrict__ dis){
  int i = blockIdx.x * 256 + threadIdx.x;
  if (i < NNODES) dis[i] = rsqrtf((float)(ecnt[i] + 1));
}

// ---------------- GCN aggregation: CSR gather, no atomics -------------------
__global__ __launch_bounds__(128)
void gcnk_aggcsr(const int* __restrict__ eoff, const int* __restrict__ ecnt,
                 const int* __restrict__ esrc, const float* __restrict__ dis,
                 const float* __restrict__ xw, float* __restrict__ agg){
  int d = blockIdx.x, t = threadIdx.x;
  float dd = dis[d];
  const float* xd = xw + (size_t)d * 150;
  float a0 = xd[t] * dd;
  float a1 = (t < 22) ? xd[128 + t] * dd : 0.f;
  int beg = eoff[d], end = beg + ecnt[d];
  for (int j = beg; j < end; j++){
    int s = esrc[j];
    float ds = dis[s];
    const float* xs = xw + (size_t)s * 150;
    a0 += xs[t] * ds;
    if (t < 22) a1 += xs[128 + t] * ds;
  }
  agg[(size_t)d * 150 + t] = a0 * dd;
  if (t < 22) agg[(size_t)d * 150 + 128 + t] = a1 * dd;
}

__global__ void gcnk_elu(float* __restrict__ h, const float* __restrict__ agg,
                         const float* __restrict__ bias){
  int idx = blockIdx.x * 256 + threadIdx.x;
  if (idx >= NNODES * 150) return;
  int c = idx % 150;
  float v = agg[idx] + bias[c];
  h[idx] = (v > 0.f) ? v : expm1f(v);
}

__global__ void gcnk_out0(float* __restrict__ out, const float* __restrict__ agg,
                          const float* __restrict__ bias){
  int idx = blockIdx.x * 256 + threadIdx.x;
  if (idx >= NNODES * 150) return;
  int c = idx % 150;
  out[idx] = agg[idx] + bias[c];
}

// ============================================================================
extern "C" void kernel_launch(void* const* d_in, const int* in_sizes, int n_in,
                              void* d_out, int out_size, void* d_ws, size_t ws_size,
                              hipStream_t stream){
  (void)in_sizes; (void)n_in; (void)out_size; (void)ws_size;

  char* wsb = (char*)d_ws;
  size_t off = 0;
  auto alloc = [&](size_t bytes) -> void* {
    void* p = wsb + off;
    off = (off + bytes + 255) & ~(size_t)255;
    return p;
  };
  float* pos_tab  = (float*)alloc(513 * 300 * 4);
  int*   sentlen  = (int*)alloc(1600 * 4);
  int*   glen     = (int*)alloc(32 * 4);
  int*   rowmap   = (int*)alloc(1600 * 4);
  float* ngram    = (float*)alloc(1600 * 300 * 4);
  float* cnn_feat = (float*)alloc(1600 * 150 * 4);
  float* cnn_rev  = (float*)alloc(1600 * 150 * 4);
  float* xih_f    = (float*)alloc(1600 * 600 * 4);
  float* xih_r    = (float*)alloc(1600 * 600 * 4);
  float* f0       = (float*)alloc(1600 * 150 * 4);
  float* r0       = (float*)alloc(1600 * 150 * 4);
  float* f1       = (float*)alloc(1600 * 150 * 4);
  float* r1       = (float*)alloc(1600 * 150 * 4);
  float* h1       = (float*)alloc(1600 * 300 * 4);
  float* h1rev    = (float*)alloc(1600 * 300 * 4);
  float* hm       = (float*)alloc(1600 * 300 * 4);
  float* lstm_ft  = (float*)alloc(1600 * 150 * 4);
  float* nodes_in = (float*)alloc((size_t)NNODES * 300 * 4);
  float* nodes    = (float*)alloc((size_t)NNODES * 150 * 4);
  float* dis      = (float*)alloc(NNODES * 4);
  float* xw       = (float*)alloc((size_t)NNODES * 150 * 4);
  float* agg      = (float*)alloc((size_t)NNODES * 150 * 4);
  _Float16* ench  = (_Float16*)alloc((size_t)MPAD * 300 * 2);
  _Float16* Bp    = (_Float16*)alloc((size_t)2 * 160 * KSTRIDE * 2);
  float* bias_p   = (float*)alloc(320 * 4);
  _Float16* wpad0 = (_Float16*)alloc(1200 * 152 * 2);
  _Float16* wpad1 = (_Float16*)alloc(1200 * 152 * 2);
  int*   ecnt     = (int*)alloc(NNODES * 4);
  int*   eoff     = (int*)alloc(NNODES * 4);
  int*   ecur     = (int*)alloc(NNODES * 4);
  int*   esrc     = (int*)alloc(EDGES * 4);

  const int*   x   = (const int*)d_in[0];
  const int*   sx  = (const int*)d_in[1];
  const int*   ei  = (const int*)d_in[2];
  const float* tab = (const float*)d_in[3];
  const float *cw[6], *cb[6];
  for (int h = 0; h < 6; h++){ cw[h] = (const float*)d_in[4 + 2 * h]; cb[h] = (const float*)d_in[5 + 2 * h]; }
  const float* cnnw = (const float*)d_in[16]; const float* cnnb = (const float*)d_in[17];
  const float* wih0 = (const float*)d_in[18]; const float* whh0 = (const float*)d_in[19];
  const float* bih0 = (const float*)d_in[20]; const float* bhh0 = (const float*)d_in[21];
  const float* wih1 = (const float*)d_in[22]; const float* whh1 = (const float*)d_in[23];
  const float* bih1 = (const float*)d_in[24]; const float* bhh1 = (const float*)d_in[25];
  const float* lpw  = (const float*)d_in[26]; const float* lpb  = (const float*)d_in[27];
  const float* g0w  = (const float*)d_in[28]; const float* g0b  = (const float*)d_in[29];
  const float* g1w  = (const float*)d_in[30]; const float* g1b  = (const float*)d_in[31];
  const float* g2w  = (const float*)d_in[32]; const float* g2b  = (const float*)d_in[33];

  float* out0 = (float*)d_out;
  float4* out1 = (float4*)((float*)d_out + OUT0SZ);

  // big-M (17600 rows): 128x64 tile; small-M (1600 rows): 64x64 tile
  auto mgemmL = [&](const float* A, const float* W, const float* b1, const float* b2,
                    float* C, int M, int N, int K){
    dim3 g((M + 127) / 128, (N + 63) / 64);
    gcnk_mgemm<128, 64, 4, 2><<<g, 256, 0, stream>>>(A, W, b1, b2, C, M, N, K);
  };
  auto mgemmS = [&](const float* A, const float* W, const float* b1, const float* b2,
                    float* C, int M, int N, int K){
    dim3 g((M + 63) / 64, (N + 63) / 64);
    gcnk_mgemm<64, 64, 2, 2><<<g, 256, 0, stream>>>(A, W, b1, b2, C, M, N, K);
  };

  // ---- pipeline ----
  gcnk_postab<<<602, 256, 0, stream>>>(pos_tab);
  gcnk_prep<<<7, 256, 0, stream>>>(sx, sentlen, glen);
  gcnk_rowmap<<<7, 256, 0, stream>>>(glen, rowmap);
  gcnk_embw<<<4688, 256, 0, stream>>>(x, tab, out1);

  // conv: fused implicit-im2col MFMA GEMM, K-split by head group
  gcnk_zeroi<<<1875, 256, 0, stream>>>((unsigned int*)ngram, 1600 * 300);
  gcnk_ench<<<(MPAD * 75 + 255) / 256, 256, 0, stream>>>(sx, tab, pos_tab, sentlen, ench);
  gcnk_bpack<<<(2 * 160 * KSTRIDE + 255) / 256, 256, 0, stream>>>(
      cw[0], cw[1], cw[2], cw[3], cw[4], cw[5],
      cb[0], cb[1], cb[2], cb[3], cb[4], cb[5], Bp, bias_p);
  gcnk_whhpack<<<713, 256, 0, stream>>>(whh0, wpad0);
  gcnk_whhpack<<<713, 256, 0, stream>>>(whh1, wpad1);
  {
    dim3 g(500, 2);
    gcnk_convmfma<<<g, 256, 0, stream>>>(ench, Bp, bias_p, (unsigned int*)ngram);
  }
  gcnk_addpos<<<1875, 256, 0, stream>>>(ngram, pos_tab);
  mgemmS(ngram, cnnw, cnnb, nullptr, cnn_feat, 1600, 150, 300);

  // BiLSTM layer 0
  gcnk_permute150<<<938, 256, 0, stream>>>(cnn_rev, cnn_feat, rowmap);
  mgemmS(cnn_feat, wih0,             bih0,       bhh0,       xih_f, 1600, 600, 150);
  mgemmS(cnn_rev,  wih0 + 600 * 150, bih0 + 600, bhh0 + 600, xih_r, 1600, 600, 150);
  gcnk_lstm<<<64, 640, 0, stream>>>(xih_f, xih_r, wpad0, f0, r0);

  // BiLSTM layer 1
  gcnk_concat<<<1875, 256, 0, stream>>>(h1,    f0, r0, nullptr, rowmap, glen, 0);
  gcnk_concat<<<1875, 256, 0, stream>>>(h1rev, f0, r0, rowmap, nullptr, glen, 0);
  mgemmS(h1,    wih1,             bih1,       bhh1,       xih_f, 1600, 600, 300);
  mgemmS(h1rev, wih1 + 600 * 300, bih1 + 600, bhh1 + 600, xih_r, 1600, 600, 300);
  gcnk_lstm<<<64, 640, 0, stream>>>(xih_f, xih_r, wpad1, f1, r1);

  // masked projection
  gcnk_concat<<<1875, 256, 0, stream>>>(hm, f1, r1, nullptr, rowmap, glen, 1);
  mgemmS(hm, lpw, lpb, nullptr, lstm_ft, 1600, 150, 300);

  // node features + gc0
  gcnk_nodes_in<<<20625, 256, 0, stream>>>(x, tab, cnn_feat, lstm_ft, nodes_in);
  mgemmL(nodes_in, g0w, g0b, nullptr, nodes, NNODES, 150, 300);

  // CSR build (once, reused by both GCN layers)
  gcnk_zeroi<<<69, 256, 0, stream>>>((unsigned int*)ecnt, NNODES);
  gcnk_hist<<<2200, 256, 0, stream>>>(ei, ecnt);
  gcnk_scan<<<1, 1024, 0, stream>>>(ecnt, eoff, ecur);
  gcnk_scatter<<<2200, 256, 0, stream>>>(ei, ecur, esrc);
  gcnk_dis2<<<69, 256, 0, stream>>>(ecnt, dis);

  // gc1 + elu
  mgemmL(nodes, g1w, nullptr, nullptr, xw, NNODES, 150, 150);
  gcnk_aggcsr<<<NNODES, 128, 0, stream>>>(eoff, ecnt, esrc, dis, xw, agg);
  gcnk_elu<<<10313, 256, 0, stream>>>(nodes, agg, g1b);

  // gc2 -> output 0
  mgemmL(nodes, g2w, nullptr, nullptr, xw, NNODES, 150, 150);
  gcnk_aggcsr<<<NNODES, 128, 0, stream>>>(eoff, ecnt, esrc, dis, xw, agg);
  gcnk_out0<<<10313, 256, 0, stream>>>(out0, agg, g2b);
}